// Round 16
// baseline (559.640 us; speedup 1.0000x reference)
//
#include <hip/hip_runtime.h>
#include <hip/hip_bf16.h>
#include <cstdint>
#include <cstddef>

#define NUSERS 200000
#define NITEMS 100000
#define UDIM 64
#define HID 128
#define ODIM 64
#define NREL 5

typedef unsigned short ushortT;
typedef __bf16 bf16x8 __attribute__((ext_vector_type(8)));
typedef __bf16 bf16x4p __attribute__((ext_vector_type(4)));
typedef float f32x4 __attribute__((ext_vector_type(4)));

static inline size_t align256(size_t x){ return (x + 255) & ~(size_t)255; }
static inline int imin(int a,int b){ return a<b?a:b; }

__device__ __forceinline__ unsigned short f2bf(float f){
  unsigned int u = __builtin_bit_cast(unsigned int, f);
  unsigned int r = (u + 0x7fffu + ((u>>16)&1u)) >> 16;   // RNE
  return (unsigned short)r;
}
__device__ __forceinline__ float b2f(unsigned short u){
  return __builtin_bit_cast(float, ((unsigned int)u)<<16);
}
__device__ __forceinline__ float blo(unsigned u){ return b2f((unsigned short)(u & 0xffff)); }
__device__ __forceinline__ float bhi(unsigned u){ return b2f((unsigned short)(u >> 16)); }
__device__ __forceinline__ uint2 pk4(float a, float b, float c, float d){
  bf16x4p t; t[0]=(__bf16)a; t[1]=(__bf16)b; t[2]=(__bf16)c; t[3]=(__bf16)d;
  return __builtin_bit_cast(uint2, t);
}
__device__ __forceinline__ void gld_lds16(const void* g, void* s){
  __builtin_amdgcn_global_load_lds((const __attribute__((address_space(1))) void*)g,
                                   (__attribute__((address_space(3))) void*)s, 16, 0, 0);
}

// ---------------- CSR build: ONE combined (node,relation) key space ----------------
// keys: item side [0, NI5), user side [NI5, NI5+NU5). adj sized 2E: peer index only.

__global__ void count_edges_k(const int* __restrict__ src, const int* __restrict__ dst,
                              const int* __restrict__ et, int E, int* __restrict__ cnt){
  int e = blockIdx.x*blockDim.x + threadIdx.x;
  if(e < E){
    int t = et[e];
    atomicAdd(&cnt[dst[e]*NREL + t], 1);
    atomicAdd(&cnt[NITEMS*NREL + src[e]*NREL + t], 1);
  }
}

__global__ __launch_bounds__(256) void scan_s1f(const int* __restrict__ c, int n, int* __restrict__ btot){
  int t = threadIdx.x;
  int base = blockIdx.x*2048 + t*8;
  int s = 0;
  #pragma unroll
  for(int j=0;j<8;++j){ int i = base+j; if(i<n) s += c[i]; }
  __shared__ int red[256];
  red[t] = s; __syncthreads();
  for(int o=128;o>0;o>>=1){ if(t<o) red[t]+=red[t+o]; __syncthreads(); }
  if(t==0) btot[blockIdx.x] = red[0];
}

__global__ __launch_bounds__(1024) void scan_s2(const int* __restrict__ btot, int nb,
                                                int* __restrict__ boff, int* __restrict__ total_out){
  __shared__ int sh[1024];
  int t = threadIdx.x;
  int v = (t<nb)? btot[t] : 0;
  sh[t] = v; __syncthreads();
  for(int o=1;o<1024;o<<=1){
    int add = (t>=o)? sh[t-o] : 0;
    __syncthreads();
    sh[t] += add;
    __syncthreads();
  }
  if(t<nb) boff[t] = sh[t]-v;
  if(t==1023) *total_out = sh[1023];
}

// writes off[i] AND cur[i] (copy for scatter) in one pass
__global__ __launch_bounds__(256) void scan_s3f(const int* __restrict__ c, int n,
                                                const int* __restrict__ boff,
                                                int* __restrict__ off, int* __restrict__ cur){
  int t = threadIdx.x, b = blockIdx.x;
  int base = b*2048 + t*8;
  int pre[8]; int s = 0;
  #pragma unroll
  for(int j=0;j<8;++j){
    int i = base+j; int d = (i<n)? c[i] : 0;
    pre[j] = s; s += d;
  }
  __shared__ int sh[256];
  sh[t] = s; __syncthreads();
  int inc = s;
  for(int o=1;o<256;o<<=1){
    int add = (t>=o)? sh[t-o] : 0;
    __syncthreads();
    sh[t] += add;
    __syncthreads();
  }
  int texcl = sh[t] - inc;
  int bo = boff[b];
  #pragma unroll
  for(int j=0;j<8;++j){
    int i = base+j;
    if(i<n){ int v = bo + texcl + pre[j]; off[i] = v; cur[i] = v; }
  }
}

// adj entries: peer node index only (rel/scale derived from segment offsets in consumers)
__global__ void scatter_k(const int* __restrict__ src, const int* __restrict__ dst,
                          const int* __restrict__ et, int E,
                          int* __restrict__ cur, int* __restrict__ adj){
  int e = blockIdx.x*blockDim.x + threadIdx.x;
  if(e < E){
    int s = src[e], d = dst[e], t = et[e];
    int p1 = atomicAdd(&cur[d*NREL + t], 1);
    adj[p1] = s;
    int p2 = atomicAdd(&cur[NITEMS*NREL + s*NREL + t], 1);
    adj[p2] = d;
  }
}

// ---------------- dtype prep ----------------

__global__ void f2bf4b_k(const float4* __restrict__ a1, int n1,
                         const float4* __restrict__ a2, int n2,
                         uint2* __restrict__ b1, uint2* __restrict__ b2){
  int i = blockIdx.x*blockDim.x + threadIdx.x;
  const float4* a; uint2* b; int idx;
  if(i < n1){ a = a1; b = b1; idx = i; }
  else if(i < n1+n2){ a = a2; b = b2; idx = i-n1; }
  else return;
  float4 v = a[idx];
  uint2 o;
  o.x = (unsigned)f2bf(v.x) | ((unsigned)f2bf(v.y)<<16);
  o.y = (unsigned)f2bf(v.z) | ((unsigned)f2bf(v.w)<<16);
  b[idx] = o;
}

// BT[Dout][6*Din] = [root; W_0..W_4]^T   (layer-1 B)
__global__ void prep_bt_k(const float* __restrict__ root, const float* __restrict__ W,
                          ushortT* __restrict__ BT, int Din, int Dout){
  int K = 6*Din;
  int idx = blockIdx.x*blockDim.x + threadIdx.x;
  if(idx >= Dout*K) return;
  int n = idx / K, k = idx % K;
  float v = (k < Din) ? root[(size_t)k*Dout + n] : W[(size_t)(k-Din)*Dout + n];
  BT[idx] = f2bf(v);
}

// BTm[R*C][K] : row n -> W[n/C][k][n%C]
__global__ void prep_w_k(const float* __restrict__ W, ushortT* __restrict__ BT,
                         int Kdim, int C, int total){
  int idx = blockIdx.x*blockDim.x + threadIdx.x;
  if(idx >= total) return;
  int n = idx / Kdim, k = idx % Kdim;
  int r = n / C, c = n % C;
  BT[idx] = f2bf(W[((size_t)r*Kdim + k)*C + c]);
}

// BTr[C][K] : row n -> root[k][n]
__global__ void prep_r_k(const float* __restrict__ root, ushortT* __restrict__ BT,
                         int Kdim, int C){
  int idx = blockIdx.x*blockDim.x + threadIdx.x;
  if(idx >= C*Kdim) return;
  int n = idx / Kdim, k = idx % Kdim;
  BT[idx] = f2bf(root[(size_t)k*C + n]);
}

// ---------------- layer-1 aggregation (D=64): 16-lane group per node ----------------

__global__ __launch_bounds__(256) void agg_m64_k(const ushortT* __restrict__ xsrc,
    const int* __restrict__ adj, const int* __restrict__ off5,
    ushortT* __restrict__ Mbuf, int cn)
{
  int gid = blockIdx.x*blockDim.x + threadIdx.x;
  int wid = gid >> 4;
  int sub = gid & 15;
  if(wid >= cn) return;
  const int* op = off5 + wid*NREL;
  int offs[6];
  #pragma unroll
  for(int r=0;r<6;++r) offs[r] = op[r];
  ushortT* mp = Mbuf + (size_t)wid*(NREL*UDIM) + sub*4;
  const ushortT* xp = xsrc + sub*4;
  #pragma unroll
  for(int r=0;r<NREL;++r){
    int e0 = offs[r], e1 = offs[r+1];
    uint2 o = {0u, 0u};
    if(e1 > e0){
      float s0=0.f, s1=0.f, s2=0.f, s3=0.f;
      for(int e=e0; e<e1; ++e){
        int p = adj[e];
        uint2 u = *(const uint2*)(xp + (size_t)p*UDIM);
        s0 += blo(u.x); s1 += bhi(u.x); s2 += blo(u.y); s3 += bhi(u.y);
      }
      float scv = 1.f/(float)(e1-e0);
      o = pk4(s0*scv, s1*scv, s2*scv, s3*scv);
    }
    *(uint2*)(mp + r*UDIM) = o;
  }
}

// ---------------- layer-2 H aggregation: 16-lane group per node, segmented ----------------
// rel = segment index; scale = 1/segment_count (computed once per nonempty segment)

__global__ __launch_bounds__(256) void agg_h_k(const ushortT* __restrict__ msg, int msgStride,
    const ushortT* __restrict__ root, int rootStride,
    const int* __restrict__ adj, const int* __restrict__ off5,
    const float* __restrict__ bias, float* __restrict__ outp, int n)
{
  int gid = blockIdx.x*blockDim.x + threadIdx.x;
  int node = gid >> 4;
  int sub = gid & 15;
  if(node >= n) return;
  const int* op = off5 + node*NREL;
  int offs[6];
  #pragma unroll
  for(int r=0;r<6;++r) offs[r] = op[r];
  float a0=0.f,a1=0.f,a2=0.f,a3=0.f;
  #pragma unroll
  for(int r=0;r<NREL;++r){
    int e0 = offs[r], e1 = offs[r+1];
    if(e1 > e0){
      const ushortT* mslice = msg + r*ODIM + sub*4;
      float s0=0.f,s1=0.f,s2=0.f,s3=0.f;
      for(int e=e0; e<e1; ++e){
        int p = adj[e];
        uint2 u = *(const uint2*)(mslice + (size_t)p*msgStride);
        s0 += blo(u.x); s1 += bhi(u.x); s2 += blo(u.y); s3 += bhi(u.y);
      }
      float scv = 1.f/(float)(e1-e0);
      a0 += s0*scv; a1 += s1*scv; a2 += s2*scv; a3 += s3*scv;
    }
  }
  uint2 rt = *(const uint2*)(root + (size_t)node*rootStride + sub*4);
  float4 bv = *(const float4*)(bias + sub*4);
  float4 o;
  o.x = a0 + blo(rt.x) + bv.x;
  o.y = a1 + bhi(rt.x) + bv.y;
  o.z = a2 + blo(rt.y) + bv.z;
  o.w = a3 + bhi(rt.y) + bv.w;
  *(float4*)(outp + (size_t)node*ODIM + sub*4) = o;
}

// ---------------- fallback M-scheme agg (layer 2, only if ws too small) ----------------

template<int D>
__global__ __launch_bounds__(256) void agg_m_k(const ushortT* __restrict__ xsrc,
    const ushortT* __restrict__ xdst, const int* __restrict__ adj,
    const int* __restrict__ off5, ushortT* __restrict__ Mbuf, int lo, int cn)
{
  int wid  = (int)((blockIdx.x*(size_t)blockDim.x + threadIdx.x) >> 6);
  int lane = threadIdx.x & 63;
  if(wid >= cn) return;
  int node = lo + wid;
  constexpr int V = D/64;
  ushortT* mp = Mbuf + (size_t)wid*(6*D);
  if(V==2) *(unsigned*)(mp + lane*2) = *(const unsigned*)(xdst + (size_t)node*D + lane*2);
  else     mp[lane] = xdst[(size_t)node*D + lane];
  #pragma unroll
  for(int r=0;r<NREL;++r){
    int base = node*NREL + r;
    int e0 = off5[base], e1 = off5[base+1];
    float s0 = 0.f, s1 = 0.f;
    for(int e=e0; e<e1; ++e){
      int p = adj[e];
      if(V==2){
        unsigned u = *(const unsigned*)(xsrc + (size_t)p*D + lane*2);
        s0 += blo(u); s1 += bhi(u);
      } else {
        s0 += b2f(xsrc[(size_t)p*D + lane]);
      }
    }
    int c = e1 - e0;
    float sc = 1.f/(float)(c>0? c:1);
    if(V==2){
      unsigned o = (unsigned)f2bf(s0*sc) | ((unsigned)f2bf(s1*sc)<<16);
      *(unsigned*)(mp + D + r*D + lane*2) = o;
    } else {
      mp[D + r*D + lane] = f2bf(s0*sc);
    }
  }
}

// ---------------- A-resident multi-slice GEMM body (K=128), operand-swapped ----------------

template<int SL>
__device__ __forceinline__ void gemmM_body(
    const ushortT* __restrict__ A, const ushortT* __restrict__ BT,
    ushortT* __restrict__ C, int ldc, int M, int bx,
    const int* __restrict__ cntKeys,
    unsigned char* sA, unsigned char* sB0, unsigned char* sB1)
{
  constexpr int K = 128, ROWB = 256;
  const int tid = threadIdx.x;
  const int w = tid >> 6, l = tid & 63;
  const int wr = w >> 1, wc = w & 1;
  const int row0 = bx * 64;

  #pragma unroll
  for(int j=0;j<4;++j){
    int c = j*256 + tid;
    int r = c >> 4;
    int jb = (c & 15) * 16;
    int grow = row0 + r; grow = (grow < M) ? grow : (M-1);
    const unsigned char* gp = (const unsigned char*)(A + (size_t)grow*K) + (jb ^ ((r&15)<<4));
    gld_lds16(gp, sA + (size_t)(j*256 + w*64)*16);
  }
  auto stageB = [&](unsigned char* sB, int s){
    const ushortT* Bp = BT + (size_t)s*64*K;
    #pragma unroll
    for(int j=0;j<4;++j){
      int c = j*256 + tid;
      int r = c >> 4;
      int jb = (c & 15) * 16;
      const unsigned char* gp = (const unsigned char*)(Bp + (size_t)r*K) + (jb ^ ((r&15)<<4));
      gld_lds16(gp, sB + (size_t)(j*256 + w*64)*16);
    }
  };
  stageB(sB0, 0);
  __syncthreads();

  bf16x8 af[4][2];
  #pragma unroll
  for(int kk=0;kk<4;++kk){
    int cb = kk*64 + (l>>4)*16;
    #pragma unroll
    for(int i=0;i<2;++i){
      int r = wr*32 + i*16 + (l&15);
      af[kk][i] = *reinterpret_cast<const bf16x8*>(sA + (size_t)r*ROWB + (cb ^ ((r&15)<<4)));
    }
  }

  f32x4 acc[SL][2][2];
  #pragma unroll
  for(int s=0;s<SL;++s)
    #pragma unroll
    for(int jc=0;jc<2;++jc)
      #pragma unroll
      for(int i=0;i<2;++i) acc[s][jc][i] = (f32x4){0.f,0.f,0.f,0.f};

  unsigned char* bufs[2] = {sB0, sB1};
  int cur = 0;
  #pragma unroll
  for(int s=0; s<SL; ++s){
    if(s+1 < SL) stageB(bufs[cur^1], s+1);
    #pragma unroll
    for(int kk=0;kk<4;++kk){
      int cb = kk*64 + (l>>4)*16;
      bf16x8 bfr[2];
      #pragma unroll
      for(int jc=0;jc<2;++jc){
        int cN = wc*32 + jc*16 + (l&15);
        bfr[jc] = *reinterpret_cast<const bf16x8*>(bufs[cur] + (size_t)cN*ROWB + (cb ^ ((cN&15)<<4)));
      }
      #pragma unroll
      for(int jc=0;jc<2;++jc)
        #pragma unroll
        for(int i=0;i<2;++i)
          acc[s][jc][i] = __builtin_amdgcn_mfma_f32_16x16x32_bf16(bfr[jc], af[kk][i], acc[s][jc][i], 0, 0, 0);
    }
    __syncthreads();
    cur ^= 1;
  }

  // predicated packed stores: skip empty (node,rel) slices when cntKeys given
  #pragma unroll
  for(int s=0;s<SL;++s){
    #pragma unroll
    for(int i=0;i<2;++i){
      int node = row0 + wr*32 + i*16 + (l&15);
      bool wr_ok = (node < M);
      if(wr_ok && cntKeys) wr_ok = (cntKeys[node*NREL + s] != 0);
      if(wr_ok){
        #pragma unroll
        for(int jc=0;jc<2;++jc){
          int c0 = s*64 + wc*32 + jc*16 + (l>>4)*4;
          uint2 v = pk4(acc[s][jc][i][0], acc[s][jc][i][1], acc[s][jc][i][2], acc[s][jc][i][3]);
          *(uint2*)(C + (size_t)node*ldc + c0) = v;
        }
      }
    }
  }
}

__global__ __launch_bounds__(256) void gemmMM_k(
    const ushortT* __restrict__ A1, const ushortT* __restrict__ BT1,
    ushortT* __restrict__ C1, int ldc1, int M1, int nt1, const int* __restrict__ cnt1,
    const ushortT* __restrict__ A2, const ushortT* __restrict__ BT2,
    ushortT* __restrict__ C2, int ldc2, int M2)
{
  __shared__ alignas(16) unsigned char sA[64*256];
  __shared__ alignas(16) unsigned char sB0[64*256];
  __shared__ alignas(16) unsigned char sB1[64*256];
  int bx = blockIdx.x;
  if(bx < nt1) gemmM_body<NREL>(A1, BT1, C1, ldc1, M1, bx, cnt1, sA, sB0, sB1);
  else         gemmM_body<1>(A2, BT2, C2, ldc2, M2, bx - nt1, nullptr, sA, sB0, sB1);
}

// ---------------- bf16 MFMA GEMM: BM=64, dbuf K-loop (layer-1 + fallback) ----------------

template<int BM, int BN, bool OUTBF, bool RELU>
__global__ __launch_bounds__(256) void gemm2v_k(
    const ushortT* __restrict__ A0, int lda0,
    const ushortT* __restrict__ A1, int lda1, int KSPLIT,
    const ushortT* __restrict__ BT, int K,
    const float* __restrict__ bias,
    void* __restrict__ Cv, int ldc, int M)
{
  constexpr int WGC = (BN>=128)? 2 : 1;
  constexpr int WGR = 4/WGC;
  constexpr int FR  = BM/(16*WGR);
  constexpr int FC  = BN/(16*WGC);
  constexpr int ACH = BM*8;
  constexpr int BCH = BN*8;
  __shared__ alignas(16) unsigned char sA[2][BM*128];
  __shared__ alignas(16) unsigned char sB[2][BN*128];

  const int tid = threadIdx.x;
  const int w = tid >> 6, l = tid & 63;
  const int wr = w / WGC, wc = w % WGC;
  const int row0 = blockIdx.y * BM;
  const int col0 = blockIdx.x * BN;
  const ushortT* BTp = BT + (size_t)col0 * K;

  f32x4 acc[FR][FC];
  #pragma unroll
  for(int i=0;i<FR;++i)
    #pragma unroll
    for(int j=0;j<FC;++j) acc[i][j] = (f32x4){0.f,0.f,0.f,0.f};

  auto stage = [&](int buf, int k0){
    const ushortT* Ab = (k0 < KSPLIT) ? A0 : A1;
    const int ldab    = (k0 < KSPLIT) ? lda0 : lda1;
    const int kc      = (k0 < KSPLIT) ? k0 : (k0 - KSPLIT);
    #pragma unroll
    for(int j=0;j<ACH/256;++j){
      int c = j*256 + tid;
      int r = c >> 3;
      int jb = (c & 7) * 16;
      int grow = row0 + r; grow = (grow < M) ? grow : (M-1);
      const unsigned char* gp = (const unsigned char*)(Ab + (size_t)grow*ldab + kc) + (jb ^ ((r&7)<<4));
      gld_lds16(gp, &sA[buf][(j*256 + w*64)*16]);
    }
    #pragma unroll
    for(int j=0;j<BCH/256;++j){
      int c = j*256 + tid;
      int r = c >> 3;
      int jb = (c & 7) * 16;
      const unsigned char* gp = (const unsigned char*)(BTp + (size_t)r*K + k0) + (jb ^ ((r&7)<<4));
      gld_lds16(gp, &sB[buf][(j*256 + w*64)*16]);
    }
  };

  const int NT = K >> 6;
  stage(0, 0);
  __syncthreads();
  int cur = 0;
  for(int t=0; t<NT; ++t){
    if(t+1 < NT) stage(cur^1, (t+1)<<6);
    #pragma unroll
    for(int kk=0;kk<2;++kk){
      const int cb = kk*64 + (l>>4)*16;
      bf16x8 af[FR], bfr[FC];
      #pragma unroll
      for(int i=0;i<FR;++i){
        int r = wr*(16*FR) + i*16 + (l&15);
        af[i] = *reinterpret_cast<const bf16x8*>(&sA[cur][r*128 + (cb ^ ((r&7)<<4))]);
      }
      #pragma unroll
      for(int j=0;j<FC;++j){
        int c = wc*(16*FC) + j*16 + (l&15);
        bfr[j] = *reinterpret_cast<const bf16x8*>(&sB[cur][c*128 + (cb ^ ((c&7)<<4))]);
      }
      #pragma unroll
      for(int i=0;i<FR;++i)
        #pragma unroll
        for(int j=0;j<FC;++j)
          acc[i][j] = __builtin_amdgcn_mfma_f32_16x16x32_bf16(af[i], bfr[j], acc[i][j], 0, 0, 0);
    }
    __syncthreads();
    cur ^= 1;
  }
  #pragma unroll
  for(int i=0;i<FR;++i){
    #pragma unroll
    for(int rr=0;rr<4;++rr){
      int grow = row0 + wr*(16*FR) + i*16 + (l>>4)*4 + rr;
      if(grow >= M) continue;
      #pragma unroll
      for(int j=0;j<FC;++j){
        int col = col0 + wc*(16*FC) + j*16 + (l&15);
        float v = acc[i][j][rr];
        if(bias) v += bias[col];
        if(RELU) v = fmaxf(v, 0.f);
        if(OUTBF) ((ushortT*)Cv)[(size_t)grow*ldc + col] = f2bf(v);
        else      ((float*)Cv)[(size_t)grow*ldc + col] = v;
      }
    }
  }
}

// ---------------- host ----------------

extern "C" void kernel_launch(void* const* d_in, const int* in_sizes, int n_in,
                              void* d_out, int out_size, void* d_ws, size_t ws_size,
                              hipStream_t stream){
  const float* x_user   = (const float*)d_in[0];
  const float* x_item   = (const float*)d_in[1];
  const int*   ei       = (const int*)d_in[2];
  const int*   et       = (const int*)d_in[3];
  const float* W1_ui    = (const float*)d_in[4];
  const float* root1_ui = (const float*)d_in[5];
  const float* b1_ui    = (const float*)d_in[6];
  const float* W1_iu    = (const float*)d_in[7];
  const float* root1_iu = (const float*)d_in[8];
  const float* b1_iu    = (const float*)d_in[9];
  const float* W2_ui    = (const float*)d_in[10];
  const float* root2_ui = (const float*)d_in[11];
  const float* b2_ui    = (const float*)d_in[12];
  const float* W2_iu    = (const float*)d_in[13];
  const float* root2_iu = (const float*)d_in[14];
  const float* b2_iu    = (const float*)d_in[15];
  const int E = in_sizes[3];
  const int* src = ei;
  const int* dst = ei + E;
  float* out = (float*)d_out;

  const int NI5 = NITEMS*NREL, NU5 = NUSERS*NREL;
  const int NK5 = NI5 + NU5;

  uint8_t* ws = (uint8_t*)d_ws;
  size_t o = 0;
  auto alloc = [&](size_t bytes){ size_t r = o; o = align256(o + bytes); return r; };
  int* cnt  = (int*)(ws + alloc((size_t)NK5*4));
  int* off  = (int*)(ws + alloc((size_t)(NK5+1)*4));
  int* cur  = (int*)(ws + alloc((size_t)NK5*4));
  int* adj  = (int*)(ws + alloc((size_t)2*E*4));
  int* btot = (int*)(ws + alloc(1024*4));
  int* boff = (int*)(ws + alloc(1024*4));
  ushortT* xu_bf = (ushortT*)(ws + alloc((size_t)NUSERS*UDIM*2));
  ushortT* xi_bf = (ushortT*)(ws + alloc((size_t)NITEMS*UDIM*2));
  ushortT* h1u   = (ushortT*)(ws + alloc((size_t)NUSERS*HID*2));
  ushortT* h1i   = (ushortT*)(ws + alloc((size_t)NITEMS*HID*2));
  ushortT* BT1ui = (ushortT*)(ws + alloc((size_t)HID*(6*UDIM)*2));
  ushortT* BT1iu = (ushortT*)(ws + alloc((size_t)HID*(6*UDIM)*2));
  ushortT* BTm2ui = (ushortT*)(ws + alloc((size_t)NREL*ODIM*HID*2));
  ushortT* BTm2iu = (ushortT*)(ws + alloc((size_t)NREL*ODIM*HID*2));
  ushortT* BTr2ui = (ushortT*)(ws + alloc((size_t)ODIM*HID*2));
  ushortT* BTr2iu = (ushortT*)(ws + alloc((size_t)ODIM*HID*2));
  ushortT* BT2ui = (ushortT*)(ws + alloc((size_t)ODIM*(6*HID)*2));   // M-fallback
  ushortT* BT2iu = (ushortT*)(ws + alloc((size_t)ODIM*(6*HID)*2));
  size_t bigoff = o;
  size_t avail = (ws_size > bigoff)? (ws_size - bigoff) : 0;
  uint8_t* big = ws + bigoff;

  const int* off_i = off;
  const int* off_u = off + NI5;
  const int* cnt_i = cnt;
  const int* cnt_u = cnt + NI5;

  size_t needH = align256((size_t)NUSERS*NREL*ODIM*2) + align256((size_t)NITEMS*ODIM*2);
  bool useH = (avail >= needH + 4096);

  // ---- CSR build (combined) ----
  hipMemsetAsync(cnt, 0, (size_t)NK5*4, stream);
  int eb = (E+255)/256;
  count_edges_k<<<eb,256,0,stream>>>(src,dst,et,E,cnt);
  int nb = (NK5+2047)/2048;
  scan_s1f<<<nb,256,0,stream>>>(cnt, NK5, btot);
  scan_s2<<<1,1024,0,stream>>>(btot, nb, boff, off+NK5);
  scan_s3f<<<nb,256,0,stream>>>(cnt, NK5, boff, off, cur);
  scatter_k<<<eb,256,0,stream>>>(src,dst,et,E,cur,adj);

  // ---- dtype prep ----
  {
    int n4u = NUSERS*UDIM/4, n4i = NITEMS*UDIM/4;
    f2bf4b_k<<<(n4u+n4i+255)/256,256,0,stream>>>(
        (const float4*)x_user, n4u, (const float4*)x_item, n4i,
        (uint2*)xu_bf, (uint2*)xi_bf);
  }
  prep_bt_k<<<(HID*6*UDIM+255)/256,256,0,stream>>>(root1_ui, W1_ui, BT1ui, UDIM, HID);
  prep_bt_k<<<(HID*6*UDIM+255)/256,256,0,stream>>>(root1_iu, W1_iu, BT1iu, UDIM, HID);
  if(useH){
    int tot = NREL*ODIM*HID;
    prep_w_k<<<(tot+255)/256,256,0,stream>>>(W2_ui, BTm2ui, HID, ODIM, tot);
    prep_w_k<<<(tot+255)/256,256,0,stream>>>(W2_iu, BTm2iu, HID, ODIM, tot);
    prep_r_k<<<(ODIM*HID+255)/256,256,0,stream>>>(root2_ui, BTr2ui, HID, ODIM);
    prep_r_k<<<(ODIM*HID+255)/256,256,0,stream>>>(root2_iu, BTr2iu, HID, ODIM);
  } else {
    prep_bt_k<<<(ODIM*6*HID+255)/256,256,0,stream>>>(root2_ui, W2_ui, BT2ui, HID, ODIM);
    prep_bt_k<<<(ODIM*6*HID+255)/256,256,0,stream>>>(root2_iu, W2_iu, BT2iu, HID, ODIM);
  }

  // ---- layer 1: M-scheme agg (no-shuffle) + gemm2v (split-A) ----
  {
    ushortT* Mbuf = (ushortT*)big;
    long long c1 = (long long)(avail / ((size_t)NREL*UDIM*2));
    int CH = (int)(c1 > 65536 ? 65536 : c1); CH &= ~127; if(CH < 128) CH = 128;
    for(int lo=0; lo<NITEMS; lo+=CH){
      int cn = imin(CH, NITEMS-lo);
      agg_m64_k<<<(cn+15)/16,256,0,stream>>>(xu_bf, adj, off_i + lo*NREL, Mbuf, cn);
      gemm2v_k<64,128,true,true><<<dim3(1,(cn+63)/64),256,0,stream>>>(
          xi_bf + (size_t)lo*UDIM, UDIM, Mbuf, NREL*UDIM, UDIM,
          BT1ui, 6*UDIM, b1_ui, h1i + (size_t)lo*HID, HID, cn);
    }
    for(int lo=0; lo<NUSERS; lo+=CH){
      int cn = imin(CH, NUSERS-lo);
      agg_m64_k<<<(cn+15)/16,256,0,stream>>>(xi_bf, adj, off_u + lo*NREL, Mbuf, cn);
      gemm2v_k<64,128,true,true><<<dim3(1,(cn+63)/64),256,0,stream>>>(
          xu_bf + (size_t)lo*UDIM, UDIM, Mbuf, NREL*UDIM, UDIM,
          BT1iu, 6*UDIM, b1_iu, h1u + (size_t)lo*HID, HID, cn);
    }
  }

  // ---- layer 2: phased H-scheme, msg+root merged per phase, msg stores predicated ----
  float* user2 = out;
  float* item2 = out + (size_t)NUSERS*ODIM;
  int ntU = (NUSERS+63)/64, ntI = (NITEMS+63)/64;
  if(useH){
    // phase A: msg user->item (SL5 over h1u, skip cnt_u==0 slices) + root item, then item agg
    ushortT* Hmsg_u  = (ushortT*)big;
    ushortT* Hroot_i = (ushortT*)(big + align256((size_t)NUSERS*NREL*ODIM*2));
    gemmMM_k<<<ntU+ntI,256,0,stream>>>(h1u, BTm2ui, Hmsg_u, NREL*ODIM, NUSERS, ntU, cnt_u,
                                       h1i, BTr2ui, Hroot_i, ODIM, NITEMS);
    agg_h_k<<<(NITEMS+15)/16,256,0,stream>>>(Hmsg_u, NREL*ODIM, Hroot_i, ODIM,
        adj, off_i, b2_ui, item2, NITEMS);
    // phase B: msg item->user (skip cnt_i==0 slices) + root user (overlay), then user agg
    ushortT* Hmsg_i  = (ushortT*)big;
    ushortT* Hroot_u = (ushortT*)(big + align256((size_t)NITEMS*NREL*ODIM*2));
    gemmMM_k<<<ntI+ntU,256,0,stream>>>(h1i, BTm2iu, Hmsg_i, NREL*ODIM, NITEMS, ntI, cnt_i,
                                       h1u, BTr2iu, Hroot_u, ODIM, NUSERS);
    agg_h_k<<<(NUSERS+15)/16,256,0,stream>>>(Hmsg_i, NREL*ODIM, Hroot_u, ODIM,
        adj, off_u, b2_iu, user2, NUSERS);
  } else {
    // fallback M-scheme
    ushortT* Mbuf = (ushortT*)big;
    long long c2 = (long long)(avail / ((size_t)6*HID*2));
    int CH = (int)(c2 > NUSERS ? NUSERS : c2); CH &= ~127; if(CH < 128) CH = 128;
    for(int lo=0; lo<NITEMS; lo+=CH){
      int cn = imin(CH, NITEMS-lo);
      agg_m_k<HID><<<(cn+3)/4,256,0,stream>>>(h1u, h1i, adj, off_i, Mbuf, lo, cn);
      gemm2v_k<64,64,false,false><<<dim3(1,(cn+63)/64),256,0,stream>>>(
          Mbuf, 6*HID, Mbuf, 6*HID, 6*HID, BT2ui, 6*HID, b2_ui, item2 + (size_t)lo*ODIM, ODIM, cn);
    }
    for(int lo=0; lo<NUSERS; lo+=CH){
      int cn = imin(CH, NUSERS-lo);
      agg_m_k<HID><<<(cn+3)/4,256,0,stream>>>(h1i, h1u, adj, off_u, Mbuf, lo, cn);
      gemm2v_k<64,64,false,false><<<dim3(1,(cn+63)/64),256,0,stream>>>(
          Mbuf, 6*HID, Mbuf, 6*HID, 6*HID, BT2iu, 6*HID, b2_iu, user2 + (size_t)lo*ODIM, ODIM, cn);
    }
  }
}

// Round 17
// 517.585 us; speedup vs baseline: 1.0813x; 1.0813x over previous
//
#include <hip/hip_runtime.h>
#include <hip/hip_bf16.h>
#include <cstdint>
#include <cstddef>

#define NUSERS 200000
#define NITEMS 100000
#define UDIM 64
#define HID 128
#define ODIM 64
#define NREL 5

typedef unsigned short ushortT;
typedef __bf16 bf16x8 __attribute__((ext_vector_type(8)));
typedef __bf16 bf16x4p __attribute__((ext_vector_type(4)));
typedef float f32x4 __attribute__((ext_vector_type(4)));

static inline size_t align256(size_t x){ return (x + 255) & ~(size_t)255; }
static inline int imin(int a,int b){ return a<b?a:b; }

__device__ __forceinline__ unsigned short f2bf(float f){
  unsigned int u = __builtin_bit_cast(unsigned int, f);
  unsigned int r = (u + 0x7fffu + ((u>>16)&1u)) >> 16;   // RNE
  return (unsigned short)r;
}
__device__ __forceinline__ float b2f(unsigned short u){
  return __builtin_bit_cast(float, ((unsigned int)u)<<16);
}
__device__ __forceinline__ float blo(unsigned u){ return b2f((unsigned short)(u & 0xffff)); }
__device__ __forceinline__ float bhi(unsigned u){ return b2f((unsigned short)(u >> 16)); }
__device__ __forceinline__ uint2 pk4(float a, float b, float c, float d){
  bf16x4p t; t[0]=(__bf16)a; t[1]=(__bf16)b; t[2]=(__bf16)c; t[3]=(__bf16)d;
  return __builtin_bit_cast(uint2, t);
}
__device__ __forceinline__ void gld_lds16(const void* g, void* s){
  __builtin_amdgcn_global_load_lds((const __attribute__((address_space(1))) void*)g,
                                   (__attribute__((address_space(3))) void*)s, 16, 0, 0);
}

// ---------------- CSR build: ONE combined (node,relation) key space ----------------
// keys: item side [0, NI5), user side [NI5, NI5+NU5). adj sized 2E: peer index only.
// count pass stores per-edge within-segment ranks -> scatter is atomic-free.

__global__ void count_edges_k(const int* __restrict__ src, const int* __restrict__ dst,
                              const int* __restrict__ et, int E,
                              int* __restrict__ cnt, int2* __restrict__ rank){
  int e = blockIdx.x*blockDim.x + threadIdx.x;
  if(e < E){
    int t = et[e];
    int r1 = atomicAdd(&cnt[dst[e]*NREL + t], 1);
    int r2 = atomicAdd(&cnt[NITEMS*NREL + src[e]*NREL + t], 1);
    rank[e] = make_int2(r1, r2);
  }
}

__global__ __launch_bounds__(256) void scan_s1f(const int* __restrict__ c, int n, int* __restrict__ btot){
  int t = threadIdx.x;
  int base = blockIdx.x*2048 + t*8;
  int s = 0;
  #pragma unroll
  for(int j=0;j<8;++j){ int i = base+j; if(i<n) s += c[i]; }
  __shared__ int red[256];
  red[t] = s; __syncthreads();
  for(int o=128;o>0;o>>=1){ if(t<o) red[t]+=red[t+o]; __syncthreads(); }
  if(t==0) btot[blockIdx.x] = red[0];
}

__global__ __launch_bounds__(1024) void scan_s2(const int* __restrict__ btot, int nb,
                                                int* __restrict__ boff, int* __restrict__ total_out){
  __shared__ int sh[1024];
  int t = threadIdx.x;
  int v = (t<nb)? btot[t] : 0;
  sh[t] = v; __syncthreads();
  for(int o=1;o<1024;o<<=1){
    int add = (t>=o)? sh[t-o] : 0;
    __syncthreads();
    sh[t] += add;
    __syncthreads();
  }
  if(t<nb) boff[t] = sh[t]-v;
  if(t==1023) *total_out = sh[1023];
}

__global__ __launch_bounds__(256) void scan_s3f(const int* __restrict__ c, int n,
                                                const int* __restrict__ boff,
                                                int* __restrict__ off){
  int t = threadIdx.x, b = blockIdx.x;
  int base = b*2048 + t*8;
  int pre[8]; int s = 0;
  #pragma unroll
  for(int j=0;j<8;++j){
    int i = base+j; int d = (i<n)? c[i] : 0;
    pre[j] = s; s += d;
  }
  __shared__ int sh[256];
  sh[t] = s; __syncthreads();
  int inc = s;
  for(int o=1;o<256;o<<=1){
    int add = (t>=o)? sh[t-o] : 0;
    __syncthreads();
    sh[t] += add;
    __syncthreads();
  }
  int texcl = sh[t] - inc;
  int bo = boff[b];
  #pragma unroll
  for(int j=0;j<8;++j){
    int i = base+j;
    if(i<n) off[i] = bo + texcl + pre[j];
  }
}

// atomic-free scatter: position = off[key] + precomputed rank
__global__ void scatter_k(const int* __restrict__ src, const int* __restrict__ dst,
                          const int* __restrict__ et, int E,
                          const int* __restrict__ off, const int2* __restrict__ rank,
                          int* __restrict__ adj){
  int e = blockIdx.x*blockDim.x + threadIdx.x;
  if(e < E){
    int s = src[e], d = dst[e], t = et[e];
    int2 r = rank[e];
    adj[off[d*NREL + t] + r.x] = s;
    adj[off[NITEMS*NREL + s*NREL + t] + r.y] = d;
  }
}

// ---------------- dtype prep ----------------

__global__ void f2bf4b_k(const float4* __restrict__ a1, int n1,
                         const float4* __restrict__ a2, int n2,
                         uint2* __restrict__ b1, uint2* __restrict__ b2){
  int i = blockIdx.x*blockDim.x + threadIdx.x;
  const float4* a; uint2* b; int idx;
  if(i < n1){ a = a1; b = b1; idx = i; }
  else if(i < n1+n2){ a = a2; b = b2; idx = i-n1; }
  else return;
  float4 v = a[idx];
  uint2 o;
  o.x = (unsigned)f2bf(v.x) | ((unsigned)f2bf(v.y)<<16);
  o.y = (unsigned)f2bf(v.z) | ((unsigned)f2bf(v.w)<<16);
  b[idx] = o;
}

// BT[Dout][6*Din] = [root; W_0..W_4]^T   (layer-1 B)
__global__ void prep_bt_k(const float* __restrict__ root, const float* __restrict__ W,
                          ushortT* __restrict__ BT, int Din, int Dout){
  int K = 6*Din;
  int idx = blockIdx.x*blockDim.x + threadIdx.x;
  if(idx >= Dout*K) return;
  int n = idx / K, k = idx % K;
  float v = (k < Din) ? root[(size_t)k*Dout + n] : W[(size_t)(k-Din)*Dout + n];
  BT[idx] = f2bf(v);
}

// BTm[R*C][K] : row n -> W[n/C][k][n%C]
__global__ void prep_w_k(const float* __restrict__ W, ushortT* __restrict__ BT,
                         int Kdim, int C, int total){
  int idx = blockIdx.x*blockDim.x + threadIdx.x;
  if(idx >= total) return;
  int n = idx / Kdim, k = idx % Kdim;
  int r = n / C, c = n % C;
  BT[idx] = f2bf(W[((size_t)r*Kdim + k)*C + c]);
}

// BTr[C][K] : row n -> root[k][n]
__global__ void prep_r_k(const float* __restrict__ root, ushortT* __restrict__ BT,
                         int Kdim, int C){
  int idx = blockIdx.x*blockDim.x + threadIdx.x;
  if(idx >= C*Kdim) return;
  int n = idx / Kdim, k = idx % Kdim;
  BT[idx] = f2bf(root[(size_t)k*C + n]);
}

// ---------------- layer-1 aggregation (D=64): 16-lane group per node ----------------

__global__ __launch_bounds__(256) void agg_m64_k(const ushortT* __restrict__ xsrc,
    const int* __restrict__ adj, const int* __restrict__ off5,
    ushortT* __restrict__ Mbuf, int cn)
{
  int gid = blockIdx.x*blockDim.x + threadIdx.x;
  int wid = gid >> 4;
  int sub = gid & 15;
  if(wid >= cn) return;
  const int* op = off5 + wid*NREL;
  int offs[6];
  #pragma unroll
  for(int r=0;r<6;++r) offs[r] = op[r];
  ushortT* mp = Mbuf + (size_t)wid*(NREL*UDIM) + sub*4;
  const ushortT* xp = xsrc + sub*4;
  #pragma unroll
  for(int r=0;r<NREL;++r){
    int e0 = offs[r], e1 = offs[r+1];
    uint2 o = {0u, 0u};
    if(e1 > e0){
      float s0=0.f, s1=0.f, s2=0.f, s3=0.f;
      for(int e=e0; e<e1; ++e){
        int p = adj[e];
        uint2 u = *(const uint2*)(xp + (size_t)p*UDIM);
        s0 += blo(u.x); s1 += bhi(u.x); s2 += blo(u.y); s3 += bhi(u.y);
      }
      float scv = 1.f/(float)(e1-e0);
      o = pk4(s0*scv, s1*scv, s2*scv, s3*scv);
    }
    *(uint2*)(mp + r*UDIM) = o;
  }
}

// ---------------- layer-2 H aggregation: 16-lane group per node, segmented ----------------

__global__ __launch_bounds__(256) void agg_h_k(const ushortT* __restrict__ msg, int msgStride,
    const ushortT* __restrict__ root, int rootStride,
    const int* __restrict__ adj, const int* __restrict__ off5,
    const float* __restrict__ bias, float* __restrict__ outp, int n)
{
  int gid = blockIdx.x*blockDim.x + threadIdx.x;
  int node = gid >> 4;
  int sub = gid & 15;
  if(node >= n) return;
  const int* op = off5 + node*NREL;
  int offs[6];
  #pragma unroll
  for(int r=0;r<6;++r) offs[r] = op[r];
  float a0=0.f,a1=0.f,a2=0.f,a3=0.f;
  #pragma unroll
  for(int r=0;r<NREL;++r){
    int e0 = offs[r], e1 = offs[r+1];
    if(e1 > e0){
      const ushortT* mslice = msg + r*ODIM + sub*4;
      float s0=0.f,s1=0.f,s2=0.f,s3=0.f;
      for(int e=e0; e<e1; ++e){
        int p = adj[e];
        uint2 u = *(const uint2*)(mslice + (size_t)p*msgStride);
        s0 += blo(u.x); s1 += bhi(u.x); s2 += blo(u.y); s3 += bhi(u.y);
      }
      float scv = 1.f/(float)(e1-e0);
      a0 += s0*scv; a1 += s1*scv; a2 += s2*scv; a3 += s3*scv;
    }
  }
  uint2 rt = *(const uint2*)(root + (size_t)node*rootStride + sub*4);
  float4 bv = *(const float4*)(bias + sub*4);
  float4 o;
  o.x = a0 + blo(rt.x) + bv.x;
  o.y = a1 + bhi(rt.x) + bv.y;
  o.z = a2 + blo(rt.y) + bv.z;
  o.w = a3 + bhi(rt.y) + bv.w;
  *(float4*)(outp + (size_t)node*ODIM + sub*4) = o;
}

// ---------------- fallback M-scheme agg (layer 2, only if ws too small) ----------------

template<int D>
__global__ __launch_bounds__(256) void agg_m_k(const ushortT* __restrict__ xsrc,
    const ushortT* __restrict__ xdst, const int* __restrict__ adj,
    const int* __restrict__ off5, ushortT* __restrict__ Mbuf, int lo, int cn)
{
  int wid  = (int)((blockIdx.x*(size_t)blockDim.x + threadIdx.x) >> 6);
  int lane = threadIdx.x & 63;
  if(wid >= cn) return;
  int node = lo + wid;
  constexpr int V = D/64;
  ushortT* mp = Mbuf + (size_t)wid*(6*D);
  if(V==2) *(unsigned*)(mp + lane*2) = *(const unsigned*)(xdst + (size_t)node*D + lane*2);
  else     mp[lane] = xdst[(size_t)node*D + lane];
  #pragma unroll
  for(int r=0;r<NREL;++r){
    int base = node*NREL + r;
    int e0 = off5[base], e1 = off5[base+1];
    float s0 = 0.f, s1 = 0.f;
    for(int e=e0; e<e1; ++e){
      int p = adj[e];
      if(V==2){
        unsigned u = *(const unsigned*)(xsrc + (size_t)p*D + lane*2);
        s0 += blo(u); s1 += bhi(u);
      } else {
        s0 += b2f(xsrc[(size_t)p*D + lane]);
      }
    }
    int c = e1 - e0;
    float sc = 1.f/(float)(c>0? c:1);
    if(V==2){
      unsigned o = (unsigned)f2bf(s0*sc) | ((unsigned)f2bf(s1*sc)<<16);
      *(unsigned*)(mp + D + r*D + lane*2) = o;
    } else {
      mp[D + r*D + lane] = f2bf(s0*sc);
    }
  }
}

// ---------------- A-resident multi-slice GEMM body (K=128), operand-swapped ----------------

template<int SL>
__device__ __forceinline__ void gemmM_body(
    const ushortT* __restrict__ A, const ushortT* __restrict__ BT,
    ushortT* __restrict__ C, int ldc, int M, int bx,
    const int* __restrict__ cntKeys,
    unsigned char* sA, unsigned char* sB0, unsigned char* sB1)
{
  constexpr int K = 128, ROWB = 256;
  const int tid = threadIdx.x;
  const int w = tid >> 6, l = tid & 63;
  const int wr = w >> 1, wc = w & 1;
  const int row0 = bx * 64;

  #pragma unroll
  for(int j=0;j<4;++j){
    int c = j*256 + tid;
    int r = c >> 4;
    int jb = (c & 15) * 16;
    int grow = row0 + r; grow = (grow < M) ? grow : (M-1);
    const unsigned char* gp = (const unsigned char*)(A + (size_t)grow*K) + (jb ^ ((r&15)<<4));
    gld_lds16(gp, sA + (size_t)(j*256 + w*64)*16);
  }
  auto stageB = [&](unsigned char* sB, int s){
    const ushortT* Bp = BT + (size_t)s*64*K;
    #pragma unroll
    for(int j=0;j<4;++j){
      int c = j*256 + tid;
      int r = c >> 4;
      int jb = (c & 15) * 16;
      const unsigned char* gp = (const unsigned char*)(Bp + (size_t)r*K) + (jb ^ ((r&15)<<4));
      gld_lds16(gp, sB + (size_t)(j*256 + w*64)*16);
    }
  };
  stageB(sB0, 0);
  __syncthreads();

  bf16x8 af[4][2];
  #pragma unroll
  for(int kk=0;kk<4;++kk){
    int cb = kk*64 + (l>>4)*16;
    #pragma unroll
    for(int i=0;i<2;++i){
      int r = wr*32 + i*16 + (l&15);
      af[kk][i] = *reinterpret_cast<const bf16x8*>(sA + (size_t)r*ROWB + (cb ^ ((r&15)<<4)));
    }
  }

  f32x4 acc[SL][2][2];
  #pragma unroll
  for(int s=0;s<SL;++s)
    #pragma unroll
    for(int jc=0;jc<2;++jc)
      #pragma unroll
      for(int i=0;i<2;++i) acc[s][jc][i] = (f32x4){0.f,0.f,0.f,0.f};

  unsigned char* bufs[2] = {sB0, sB1};
  int cur = 0;
  #pragma unroll
  for(int s=0; s<SL; ++s){
    if(s+1 < SL) stageB(bufs[cur^1], s+1);
    #pragma unroll
    for(int kk=0;kk<4;++kk){
      int cb = kk*64 + (l>>4)*16;
      bf16x8 bfr[2];
      #pragma unroll
      for(int jc=0;jc<2;++jc){
        int cN = wc*32 + jc*16 + (l&15);
        bfr[jc] = *reinterpret_cast<const bf16x8*>(bufs[cur] + (size_t)cN*ROWB + (cb ^ ((cN&15)<<4)));
      }
      #pragma unroll
      for(int jc=0;jc<2;++jc)
        #pragma unroll
        for(int i=0;i<2;++i)
          acc[s][jc][i] = __builtin_amdgcn_mfma_f32_16x16x32_bf16(bfr[jc], af[kk][i], acc[s][jc][i], 0, 0, 0);
    }
    __syncthreads();
    cur ^= 1;
  }

  #pragma unroll
  for(int s=0;s<SL;++s){
    #pragma unroll
    for(int i=0;i<2;++i){
      int node = row0 + wr*32 + i*16 + (l&15);
      bool wr_ok = (node < M);
      if(wr_ok && cntKeys) wr_ok = (cntKeys[node*NREL + s] != 0);
      if(wr_ok){
        #pragma unroll
        for(int jc=0;jc<2;++jc){
          int c0 = s*64 + wc*32 + jc*16 + (l>>4)*4;
          uint2 v = pk4(acc[s][jc][i][0], acc[s][jc][i][1], acc[s][jc][i][2], acc[s][jc][i][3]);
          *(uint2*)(C + (size_t)node*ldc + c0) = v;
        }
      }
    }
  }
}

__global__ __launch_bounds__(256) void gemmMM_k(
    const ushortT* __restrict__ A1, const ushortT* __restrict__ BT1,
    ushortT* __restrict__ C1, int ldc1, int M1, int nt1, const int* __restrict__ cnt1,
    const ushortT* __restrict__ A2, const ushortT* __restrict__ BT2,
    ushortT* __restrict__ C2, int ldc2, int M2)
{
  __shared__ alignas(16) unsigned char sA[64*256];
  __shared__ alignas(16) unsigned char sB0[64*256];
  __shared__ alignas(16) unsigned char sB1[64*256];
  int bx = blockIdx.x;
  if(bx < nt1) gemmM_body<NREL>(A1, BT1, C1, ldc1, M1, bx, cnt1, sA, sB0, sB1);
  else         gemmM_body<1>(A2, BT2, C2, ldc2, M2, bx - nt1, nullptr, sA, sB0, sB1);
}

// ---------------- bf16 MFMA GEMM: BM=64, dbuf K-loop (layer-1 + fallback) ----------------

template<int BM, int BN, bool OUTBF, bool RELU>
__global__ __launch_bounds__(256) void gemm2v_k(
    const ushortT* __restrict__ A0, int lda0,
    const ushortT* __restrict__ A1, int lda1, int KSPLIT,
    const ushortT* __restrict__ BT, int K,
    const float* __restrict__ bias,
    void* __restrict__ Cv, int ldc, int M)
{
  constexpr int WGC = (BN>=128)? 2 : 1;
  constexpr int WGR = 4/WGC;
  constexpr int FR  = BM/(16*WGR);
  constexpr int FC  = BN/(16*WGC);
  constexpr int ACH = BM*8;
  constexpr int BCH = BN*8;
  __shared__ alignas(16) unsigned char sA[2][BM*128];
  __shared__ alignas(16) unsigned char sB[2][BN*128];

  const int tid = threadIdx.x;
  const int w = tid >> 6, l = tid & 63;
  const int wr = w / WGC, wc = w % WGC;
  const int row0 = blockIdx.y * BM;
  const int col0 = blockIdx.x * BN;
  const ushortT* BTp = BT + (size_t)col0 * K;

  f32x4 acc[FR][FC];
  #pragma unroll
  for(int i=0;i<FR;++i)
    #pragma unroll
    for(int j=0;j<FC;++j) acc[i][j] = (f32x4){0.f,0.f,0.f,0.f};

  auto stage = [&](int buf, int k0){
    const ushortT* Ab = (k0 < KSPLIT) ? A0 : A1;
    const int ldab    = (k0 < KSPLIT) ? lda0 : lda1;
    const int kc      = (k0 < KSPLIT) ? k0 : (k0 - KSPLIT);
    #pragma unroll
    for(int j=0;j<ACH/256;++j){
      int c = j*256 + tid;
      int r = c >> 3;
      int jb = (c & 7) * 16;
      int grow = row0 + r; grow = (grow < M) ? grow : (M-1);
      const unsigned char* gp = (const unsigned char*)(Ab + (size_t)grow*ldab + kc) + (jb ^ ((r&7)<<4));
      gld_lds16(gp, &sA[buf][(j*256 + w*64)*16]);
    }
    #pragma unroll
    for(int j=0;j<BCH/256;++j){
      int c = j*256 + tid;
      int r = c >> 3;
      int jb = (c & 7) * 16;
      const unsigned char* gp = (const unsigned char*)(BTp + (size_t)r*K + k0) + (jb ^ ((r&7)<<4));
      gld_lds16(gp, &sB[buf][(j*256 + w*64)*16]);
    }
  };

  const int NT = K >> 6;
  stage(0, 0);
  __syncthreads();
  int cur = 0;
  for(int t=0; t<NT; ++t){
    if(t+1 < NT) stage(cur^1, (t+1)<<6);
    #pragma unroll
    for(int kk=0;kk<2;++kk){
      const int cb = kk*64 + (l>>4)*16;
      bf16x8 af[FR], bfr[FC];
      #pragma unroll
      for(int i=0;i<FR;++i){
        int r = wr*(16*FR) + i*16 + (l&15);
        af[i] = *reinterpret_cast<const bf16x8*>(&sA[cur][r*128 + (cb ^ ((r&7)<<4))]);
      }
      #pragma unroll
      for(int j=0;j<FC;++j){
        int c = wc*(16*FC) + j*16 + (l&15);
        bfr[j] = *reinterpret_cast<const bf16x8*>(&sB[cur][c*128 + (cb ^ ((c&7)<<4))]);
      }
      #pragma unroll
      for(int i=0;i<FR;++i)
        #pragma unroll
        for(int j=0;j<FC;++j)
          acc[i][j] = __builtin_amdgcn_mfma_f32_16x16x32_bf16(af[i], bfr[j], acc[i][j], 0, 0, 0);
    }
    __syncthreads();
    cur ^= 1;
  }
  #pragma unroll
  for(int i=0;i<FR;++i){
    #pragma unroll
    for(int rr=0;rr<4;++rr){
      int grow = row0 + wr*(16*FR) + i*16 + (l>>4)*4 + rr;
      if(grow >= M) continue;
      #pragma unroll
      for(int j=0;j<FC;++j){
        int col = col0 + wc*(16*FC) + j*16 + (l&15);
        float v = acc[i][j][rr];
        if(bias) v += bias[col];
        if(RELU) v = fmaxf(v, 0.f);
        if(OUTBF) ((ushortT*)Cv)[(size_t)grow*ldc + col] = f2bf(v);
        else      ((float*)Cv)[(size_t)grow*ldc + col] = v;
      }
    }
  }
}

// ---------------- host ----------------

extern "C" void kernel_launch(void* const* d_in, const int* in_sizes, int n_in,
                              void* d_out, int out_size, void* d_ws, size_t ws_size,
                              hipStream_t stream){
  const float* x_user   = (const float*)d_in[0];
  const float* x_item   = (const float*)d_in[1];
  const int*   ei       = (const int*)d_in[2];
  const int*   et       = (const int*)d_in[3];
  const float* W1_ui    = (const float*)d_in[4];
  const float* root1_ui = (const float*)d_in[5];
  const float* b1_ui    = (const float*)d_in[6];
  const float* W1_iu    = (const float*)d_in[7];
  const float* root1_iu = (const float*)d_in[8];
  const float* b1_iu    = (const float*)d_in[9];
  const float* W2_ui    = (const float*)d_in[10];
  const float* root2_ui = (const float*)d_in[11];
  const float* b2_ui    = (const float*)d_in[12];
  const float* W2_iu    = (const float*)d_in[13];
  const float* root2_iu = (const float*)d_in[14];
  const float* b2_iu    = (const float*)d_in[15];
  const int E = in_sizes[3];
  const int* src = ei;
  const int* dst = ei + E;
  float* out = (float*)d_out;

  const int NI5 = NITEMS*NREL, NU5 = NUSERS*NREL;
  const int NK5 = NI5 + NU5;

  uint8_t* ws = (uint8_t*)d_ws;
  size_t o = 0;
  auto alloc = [&](size_t bytes){ size_t r = o; o = align256(o + bytes); return r; };
  int* cnt  = (int*)(ws + alloc((size_t)NK5*4));
  int* off  = (int*)(ws + alloc((size_t)(NK5+1)*4));
  int2* rank= (int2*)(ws + alloc((size_t)E*8));
  int* adj  = (int*)(ws + alloc((size_t)2*E*4));
  int* btot = (int*)(ws + alloc(1024*4));
  int* boff = (int*)(ws + alloc(1024*4));
  ushortT* xu_bf = (ushortT*)(ws + alloc((size_t)NUSERS*UDIM*2));
  ushortT* xi_bf = (ushortT*)(ws + alloc((size_t)NITEMS*UDIM*2));
  ushortT* h1u   = (ushortT*)(ws + alloc((size_t)NUSERS*HID*2));
  ushortT* h1i   = (ushortT*)(ws + alloc((size_t)NITEMS*HID*2));
  ushortT* BT1ui = (ushortT*)(ws + alloc((size_t)HID*(6*UDIM)*2));
  ushortT* BT1iu = (ushortT*)(ws + alloc((size_t)HID*(6*UDIM)*2));
  ushortT* BTm2ui = (ushortT*)(ws + alloc((size_t)NREL*ODIM*HID*2));
  ushortT* BTm2iu = (ushortT*)(ws + alloc((size_t)NREL*ODIM*HID*2));
  ushortT* BTr2ui = (ushortT*)(ws + alloc((size_t)ODIM*HID*2));
  ushortT* BTr2iu = (ushortT*)(ws + alloc((size_t)ODIM*HID*2));
  ushortT* BT2ui = (ushortT*)(ws + alloc((size_t)ODIM*(6*HID)*2));   // M-fallback
  ushortT* BT2iu = (ushortT*)(ws + alloc((size_t)ODIM*(6*HID)*2));
  size_t bigoff = o;
  size_t avail = (ws_size > bigoff)? (ws_size - bigoff) : 0;
  uint8_t* big = ws + bigoff;

  const int* off_i = off;
  const int* off_u = off + NI5;
  const int* cnt_i = cnt;
  const int* cnt_u = cnt + NI5;

  size_t needH = align256((size_t)NUSERS*NREL*ODIM*2) + align256((size_t)NITEMS*ODIM*2);
  bool useH = (avail >= needH + 4096);

  // ---- CSR build (combined; count records ranks, scatter is atomic-free) ----
  hipMemsetAsync(cnt, 0, (size_t)NK5*4, stream);
  int eb = (E+255)/256;
  count_edges_k<<<eb,256,0,stream>>>(src,dst,et,E,cnt,rank);
  int nb = (NK5+2047)/2048;
  scan_s1f<<<nb,256,0,stream>>>(cnt, NK5, btot);
  scan_s2<<<1,1024,0,stream>>>(btot, nb, boff, off+NK5);
  scan_s3f<<<nb,256,0,stream>>>(cnt, NK5, boff, off);
  scatter_k<<<eb,256,0,stream>>>(src,dst,et,E,off,rank,adj);

  // ---- dtype prep ----
  {
    int n4u = NUSERS*UDIM/4, n4i = NITEMS*UDIM/4;
    f2bf4b_k<<<(n4u+n4i+255)/256,256,0,stream>>>(
        (const float4*)x_user, n4u, (const float4*)x_item, n4i,
        (uint2*)xu_bf, (uint2*)xi_bf);
  }
  prep_bt_k<<<(HID*6*UDIM+255)/256,256,0,stream>>>(root1_ui, W1_ui, BT1ui, UDIM, HID);
  prep_bt_k<<<(HID*6*UDIM+255)/256,256,0,stream>>>(root1_iu, W1_iu, BT1iu, UDIM, HID);
  if(useH){
    int tot = NREL*ODIM*HID;
    prep_w_k<<<(tot+255)/256,256,0,stream>>>(W2_ui, BTm2ui, HID, ODIM, tot);
    prep_w_k<<<(tot+255)/256,256,0,stream>>>(W2_iu, BTm2iu, HID, ODIM, tot);
    prep_r_k<<<(ODIM*HID+255)/256,256,0,stream>>>(root2_ui, BTr2ui, HID, ODIM);
    prep_r_k<<<(ODIM*HID+255)/256,256,0,stream>>>(root2_iu, BTr2iu, HID, ODIM);
  } else {
    prep_bt_k<<<(ODIM*6*HID+255)/256,256,0,stream>>>(root2_ui, W2_ui, BT2ui, HID, ODIM);
    prep_bt_k<<<(ODIM*6*HID+255)/256,256,0,stream>>>(root2_iu, W2_iu, BT2iu, HID, ODIM);
  }

  // ---- layer 1: M-scheme agg (no-shuffle) + gemm2v (split-A) ----
  {
    ushortT* Mbuf = (ushortT*)big;
    long long c1 = (long long)(avail / ((size_t)NREL*UDIM*2));
    int CH = (int)(c1 > 65536 ? 65536 : c1); CH &= ~127; if(CH < 128) CH = 128;
    for(int lo=0; lo<NITEMS; lo+=CH){
      int cn = imin(CH, NITEMS-lo);
      agg_m64_k<<<(cn+15)/16,256,0,stream>>>(xu_bf, adj, off_i + lo*NREL, Mbuf, cn);
      gemm2v_k<64,128,true,true><<<dim3(1,(cn+63)/64),256,0,stream>>>(
          xi_bf + (size_t)lo*UDIM, UDIM, Mbuf, NREL*UDIM, UDIM,
          BT1ui, 6*UDIM, b1_ui, h1i + (size_t)lo*HID, HID, cn);
    }
    for(int lo=0; lo<NUSERS; lo+=CH){
      int cn = imin(CH, NUSERS-lo);
      agg_m64_k<<<(cn+15)/16,256,0,stream>>>(xi_bf, adj, off_u + lo*NREL, Mbuf, cn);
      gemm2v_k<64,128,true,true><<<dim3(1,(cn+63)/64),256,0,stream>>>(
          xu_bf + (size_t)lo*UDIM, UDIM, Mbuf, NREL*UDIM, UDIM,
          BT1iu, 6*UDIM, b1_iu, h1u + (size_t)lo*HID, HID, cn);
    }
  }

  // ---- layer 2: phased H-scheme, msg+root merged per phase, msg stores predicated ----
  float* user2 = out;
  float* item2 = out + (size_t)NUSERS*ODIM;
  int ntU = (NUSERS+63)/64, ntI = (NITEMS+63)/64;
  if(useH){
    // phase A: msg user->item (SL5 over h1u, skip cnt_u==0 slices) + root item, then item agg
    ushortT* Hmsg_u  = (ushortT*)big;
    ushortT* Hroot_i = (ushortT*)(big + align256((size_t)NUSERS*NREL*ODIM*2));
    gemmMM_k<<<ntU+ntI,256,0,stream>>>(h1u, BTm2ui, Hmsg_u, NREL*ODIM, NUSERS, ntU, cnt_u,
                                       h1i, BTr2ui, Hroot_i, ODIM, NITEMS);
    agg_h_k<<<(NITEMS+15)/16,256,0,stream>>>(Hmsg_u, NREL*ODIM, Hroot_i, ODIM,
        adj, off_i, b2_ui, item2, NITEMS);
    // phase B: msg item->user (skip cnt_i==0 slices) + root user (overlay), then user agg
    ushortT* Hmsg_i  = (ushortT*)big;
    ushortT* Hroot_u = (ushortT*)(big + align256((size_t)NITEMS*NREL*ODIM*2));
    gemmMM_k<<<ntI+ntU,256,0,stream>>>(h1i, BTm2iu, Hmsg_i, NREL*ODIM, NITEMS, ntI, cnt_i,
                                       h1u, BTr2iu, Hroot_u, ODIM, NUSERS);
    agg_h_k<<<(NUSERS+15)/16,256,0,stream>>>(Hmsg_i, NREL*ODIM, Hroot_u, ODIM,
        adj, off_u, b2_iu, user2, NUSERS);
  } else {
    // fallback M-scheme
    ushortT* Mbuf = (ushortT*)big;
    long long c2 = (long long)(avail / ((size_t)6*HID*2));
    int CH = (int)(c2 > NUSERS ? NUSERS : c2); CH &= ~127; if(CH < 128) CH = 128;
    for(int lo=0; lo<NITEMS; lo+=CH){
      int cn = imin(CH, NITEMS-lo);
      agg_m_k<HID><<<(cn+3)/4,256,0,stream>>>(h1u, h1i, adj, off_i, Mbuf, lo, cn);
      gemm2v_k<64,64,false,false><<<dim3(1,(cn+63)/64),256,0,stream>>>(
          Mbuf, 6*HID, Mbuf, 6*HID, 6*HID, BT2ui, 6*HID, b2_ui, item2 + (size_t)lo*ODIM, ODIM, cn);
    }
    for(int lo=0; lo<NUSERS; lo+=CH){
      int cn = imin(CH, NUSERS-lo);
      agg_m_k<HID><<<(cn+3)/4,256,0,stream>>>(h1i, h1u, adj, off_u, Mbuf, lo, cn);
      gemm2v_k<64,64,false,false><<<dim3(1,(cn+63)/64),256,0,stream>>>(
          Mbuf, 6*HID, Mbuf, 6*HID, 6*HID, BT2iu, 6*HID, b2_iu, user2 + (size_t)lo*ODIM, ODIM, cn);
    }
  }
}

// Round 19
// 515.717 us; speedup vs baseline: 1.0852x; 1.0036x over previous
//
#include <hip/hip_runtime.h>
#include <hip/hip_bf16.h>
#include <cstdint>
#include <cstddef>

#define NUSERS 200000
#define NITEMS 100000
#define UDIM 64
#define HID 128
#define ODIM 64
#define NREL 5

typedef unsigned short ushortT;
typedef __bf16 bf16x8 __attribute__((ext_vector_type(8)));
typedef __bf16 bf16x4p __attribute__((ext_vector_type(4)));
typedef float f32x4 __attribute__((ext_vector_type(4)));

static inline size_t align256(size_t x){ return (x + 255) & ~(size_t)255; }
static inline int imin(int a,int b){ return a<b?a:b; }

__device__ __forceinline__ unsigned short f2bf(float f){
  unsigned int u = __builtin_bit_cast(unsigned int, f);
  unsigned int r = (u + 0x7fffu + ((u>>16)&1u)) >> 16;   // RNE
  return (unsigned short)r;
}
__device__ __forceinline__ float b2f(unsigned short u){
  return __builtin_bit_cast(float, ((unsigned int)u)<<16);
}
__device__ __forceinline__ float blo(unsigned u){ return b2f((unsigned short)(u & 0xffff)); }
__device__ __forceinline__ float bhi(unsigned u){ return b2f((unsigned short)(u >> 16)); }
__device__ __forceinline__ uint2 pk4(float a, float b, float c, float d){
  bf16x4p t; t[0]=(__bf16)a; t[1]=(__bf16)b; t[2]=(__bf16)c; t[3]=(__bf16)d;
  return __builtin_bit_cast(uint2, t);
}
__device__ __forceinline__ void gld_lds16(const void* g, void* s){
  __builtin_amdgcn_global_load_lds((const __attribute__((address_space(1))) void*)g,
                                   (__attribute__((address_space(3))) void*)s, 16, 0, 0);
}

// ---------------- CSR build: ONE combined (node,relation) key space ----------------
// count pass stores per-edge within-segment ranks -> scatter is atomic-free.

__global__ void count_edges_k(const int* __restrict__ src, const int* __restrict__ dst,
                              const int* __restrict__ et, int E,
                              int* __restrict__ cnt, int2* __restrict__ rank){
  int e = blockIdx.x*blockDim.x + threadIdx.x;
  if(e < E){
    int t = et[e];
    int r1 = atomicAdd(&cnt[dst[e]*NREL + t], 1);
    int r2 = atomicAdd(&cnt[NITEMS*NREL + src[e]*NREL + t], 1);
    rank[e] = make_int2(r1, r2);
  }
}

__global__ __launch_bounds__(256) void scan_s1f(const int* __restrict__ c, int n, int* __restrict__ btot){
  int t = threadIdx.x;
  int base = blockIdx.x*2048 + t*8;
  int s = 0;
  #pragma unroll
  for(int j=0;j<8;++j){ int i = base+j; if(i<n) s += c[i]; }
  __shared__ int red[256];
  red[t] = s; __syncthreads();
  for(int o=128;o>0;o>>=1){ if(t<o) red[t]+=red[t+o]; __syncthreads(); }
  if(t==0) btot[blockIdx.x] = red[0];
}

__global__ __launch_bounds__(1024) void scan_s2(const int* __restrict__ btot, int nb,
                                                int* __restrict__ boff, int* __restrict__ total_out){
  __shared__ int sh[1024];
  int t = threadIdx.x;
  int v = (t<nb)? btot[t] : 0;
  sh[t] = v; __syncthreads();
  for(int o=1;o<1024;o<<=1){
    int add = (t>=o)? sh[t-o] : 0;
    __syncthreads();
    sh[t] += add;
    __syncthreads();
  }
  if(t<nb) boff[t] = sh[t]-v;
  if(t==1023) *total_out = sh[1023];
}

__global__ __launch_bounds__(256) void scan_s3f(const int* __restrict__ c, int n,
                                                const int* __restrict__ boff,
                                                int* __restrict__ off){
  int t = threadIdx.x, b = blockIdx.x;
  int base = b*2048 + t*8;
  int pre[8]; int s = 0;
  #pragma unroll
  for(int j=0;j<8;++j){
    int i = base+j; int d = (i<n)? c[i] : 0;
    pre[j] = s; s += d;
  }
  __shared__ int sh[256];
  sh[t] = s; __syncthreads();
  int inc = s;
  for(int o=1;o<256;o<<=1){
    int add = (t>=o)? sh[t-o] : 0;
    __syncthreads();
    sh[t] += add;
    __syncthreads();
  }
  int texcl = sh[t] - inc;
  int bo = boff[b];
  #pragma unroll
  for(int j=0;j<8;++j){
    int i = base+j;
    if(i<n) off[i] = bo + texcl + pre[j];
  }
}

// atomic-free scatter: position = off[key] + precomputed rank
__global__ void scatter_k(const int* __restrict__ src, const int* __restrict__ dst,
                          const int* __restrict__ et, int E,
                          const int* __restrict__ off, const int2* __restrict__ rank,
                          int* __restrict__ adj){
  int e = blockIdx.x*blockDim.x + threadIdx.x;
  if(e < E){
    int s = src[e], d = dst[e], t = et[e];
    int2 r = rank[e];
    adj[off[d*NREL + t] + r.x] = s;
    adj[off[NITEMS*NREL + s*NREL + t] + r.y] = d;
  }
}

// ---------------- dtype prep ----------------

__global__ void f2bf4b_k(const float4* __restrict__ a1, int n1,
                         const float4* __restrict__ a2, int n2,
                         uint2* __restrict__ b1, uint2* __restrict__ b2){
  int i = blockIdx.x*blockDim.x + threadIdx.x;
  const float4* a; uint2* b; int idx;
  if(i < n1){ a = a1; b = b1; idx = i; }
  else if(i < n1+n2){ a = a2; b = b2; idx = i-n1; }
  else return;
  float4 v = a[idx];
  uint2 o;
  o.x = (unsigned)f2bf(v.x) | ((unsigned)f2bf(v.y)<<16);
  o.y = (unsigned)f2bf(v.z) | ((unsigned)f2bf(v.w)<<16);
  b[idx] = o;
}

// BT[Dout][6*Din] = [root; W_0..W_4]^T   (layer-1 B)
__global__ void prep_bt_k(const float* __restrict__ root, const float* __restrict__ W,
                          ushortT* __restrict__ BT, int Din, int Dout){
  int K = 6*Din;
  int idx = blockIdx.x*blockDim.x + threadIdx.x;
  if(idx >= Dout*K) return;
  int n = idx / K, k = idx % K;
  float v = (k < Din) ? root[(size_t)k*Dout + n] : W[(size_t)(k-Din)*Dout + n];
  BT[idx] = f2bf(v);
}

// BTm[R*C][K] : row n -> W[n/C][k][n%C]
__global__ void prep_w_k(const float* __restrict__ W, ushortT* __restrict__ BT,
                         int Kdim, int C, int total){
  int idx = blockIdx.x*blockDim.x + threadIdx.x;
  if(idx >= total) return;
  int n = idx / Kdim, k = idx % Kdim;
  int r = n / C, c = n % C;
  BT[idx] = f2bf(W[((size_t)r*Kdim + k)*C + c]);
}

// BTr[C][K] : row n -> root[k][n]
__global__ void prep_r_k(const float* __restrict__ root, ushortT* __restrict__ BT,
                         int Kdim, int C){
  int idx = blockIdx.x*blockDim.x + threadIdx.x;
  if(idx >= C*Kdim) return;
  int n = idx / Kdim, k = idx % Kdim;
  BT[idx] = f2bf(root[(size_t)k*C + n]);
}

// ---------------- layer-1 aggregation (D=64): 16-lane group per node ----------------

__global__ __launch_bounds__(256) void agg_m64_k(const ushortT* __restrict__ xsrc,
    const int* __restrict__ adj, const int* __restrict__ off5,
    ushortT* __restrict__ Mbuf, int cn)
{
  int gid = blockIdx.x*blockDim.x + threadIdx.x;
  int wid = gid >> 4;
  int sub = gid & 15;
  if(wid >= cn) return;
  const int* op = off5 + wid*NREL;
  int offs[6];
  #pragma unroll
  for(int r=0;r<6;++r) offs[r] = op[r];
  ushortT* mp = Mbuf + (size_t)wid*(NREL*UDIM) + sub*4;
  const ushortT* xp = xsrc + sub*4;
  #pragma unroll
  for(int r=0;r<NREL;++r){
    int e0 = offs[r], e1 = offs[r+1];
    uint2 o = {0u, 0u};
    if(e1 > e0){
      float s0=0.f, s1=0.f, s2=0.f, s3=0.f;
      for(int e=e0; e<e1; ++e){
        int p = adj[e];
        uint2 u = *(const uint2*)(xp + (size_t)p*UDIM);
        s0 += blo(u.x); s1 += bhi(u.x); s2 += blo(u.y); s3 += bhi(u.y);
      }
      float scv = 1.f/(float)(e1-e0);
      o = pk4(s0*scv, s1*scv, s2*scv, s3*scv);
    }
    *(uint2*)(mp + r*UDIM) = o;
  }
}

// ---------------- layer-2 H aggregation: 16-lane group per node, segmented ----------------

__global__ __launch_bounds__(256) void agg_h_k(const ushortT* __restrict__ msg, int msgStride,
    const ushortT* __restrict__ root, int rootStride,
    const int* __restrict__ adj, const int* __restrict__ off5,
    const float* __restrict__ bias, float* __restrict__ outp, int n)
{
  int gid = blockIdx.x*blockDim.x + threadIdx.x;
  int node = gid >> 4;
  int sub = gid & 15;
  if(node >= n) return;
  const int* op = off5 + node*NREL;
  int offs[6];
  #pragma unroll
  for(int r=0;r<6;++r) offs[r] = op[r];
  float a0=0.f,a1=0.f,a2=0.f,a3=0.f;
  #pragma unroll
  for(int r=0;r<NREL;++r){
    int e0 = offs[r], e1 = offs[r+1];
    if(e1 > e0){
      const ushortT* mslice = msg + r*ODIM + sub*4;
      float s0=0.f,s1=0.f,s2=0.f,s3=0.f;
      for(int e=e0; e<e1; ++e){
        int p = adj[e];
        uint2 u = *(const uint2*)(mslice + (size_t)p*msgStride);
        s0 += blo(u.x); s1 += bhi(u.x); s2 += blo(u.y); s3 += bhi(u.y);
      }
      float scv = 1.f/(float)(e1-e0);
      a0 += s0*scv; a1 += s1*scv; a2 += s2*scv; a3 += s3*scv;
    }
  }
  uint2 rt = *(const uint2*)(root + (size_t)node*rootStride + sub*4);
  float4 bv = *(const float4*)(bias + sub*4);
  float4 o;
  o.x = a0 + blo(rt.x) + bv.x;
  o.y = a1 + bhi(rt.x) + bv.y;
  o.z = a2 + blo(rt.y) + bv.z;
  o.w = a3 + bhi(rt.y) + bv.w;
  *(float4*)(outp + (size_t)node*ODIM + sub*4) = o;
}

// ---------------- fallback M-scheme agg (layer 2, only if ws too small) ----------------

template<int D>
__global__ __launch_bounds__(256) void agg_m_k(const ushortT* __restrict__ xsrc,
    const ushortT* __restrict__ xdst, const int* __restrict__ adj,
    const int* __restrict__ off5, ushortT* __restrict__ Mbuf, int lo, int cn)
{
  int wid  = (int)((blockIdx.x*(size_t)blockDim.x + threadIdx.x) >> 6);
  int lane = threadIdx.x & 63;
  if(wid >= cn) return;
  int node = lo + wid;
  constexpr int V = D/64;
  ushortT* mp = Mbuf + (size_t)wid*(6*D);
  if(V==2) *(unsigned*)(mp + lane*2) = *(const unsigned*)(xdst + (size_t)node*D + lane*2);
  else     mp[lane] = xdst[(size_t)node*D + lane];
  #pragma unroll
  for(int r=0;r<NREL;++r){
    int base = node*NREL + r;
    int e0 = off5[base], e1 = off5[base+1];
    float s0 = 0.f, s1 = 0.f;
    for(int e=e0; e<e1; ++e){
      int p = adj[e];
      if(V==2){
        unsigned u = *(const unsigned*)(xsrc + (size_t)p*D + lane*2);
        s0 += blo(u); s1 += bhi(u);
      } else {
        s0 += b2f(xsrc[(size_t)p*D + lane]);
      }
    }
    int c = e1 - e0;
    float sc = 1.f/(float)(c>0? c:1);
    if(V==2){
      unsigned o = (unsigned)f2bf(s0*sc) | ((unsigned)f2bf(s1*sc)<<16);
      *(unsigned*)(mp + D + r*D + lane*2) = o;
    } else {
      mp[D + r*D + lane] = f2bf(s0*sc);
    }
  }
}

// ---------------- A-resident multi-slice GEMM body (K=128), operand-swapped ----------------
// (round-17 verified structure: dedicated sB0/sB1 double-buffer, NO sA aliasing)

template<int SL>
__device__ __forceinline__ void gemmM_body(
    const ushortT* __restrict__ A, const ushortT* __restrict__ BT,
    ushortT* __restrict__ C, int ldc, int M, int bx,
    const int* __restrict__ cntKeys,
    unsigned char* sA, unsigned char* sB0, unsigned char* sB1)
{
  constexpr int K = 128, ROWB = 256;
  const int tid = threadIdx.x;
  const int w = tid >> 6, l = tid & 63;
  const int wr = w >> 1, wc = w & 1;
  const int row0 = bx * 64;

  #pragma unroll
  for(int j=0;j<4;++j){
    int c = j*256 + tid;
    int r = c >> 4;
    int jb = (c & 15) * 16;
    int grow = row0 + r; grow = (grow < M) ? grow : (M-1);
    const unsigned char* gp = (const unsigned char*)(A + (size_t)grow*K) + (jb ^ ((r&15)<<4));
    gld_lds16(gp, sA + (size_t)(j*256 + w*64)*16);
  }
  auto stageB = [&](unsigned char* sB, int s){
    const ushortT* Bp = BT + (size_t)s*64*K;
    #pragma unroll
    for(int j=0;j<4;++j){
      int c = j*256 + tid;
      int r = c >> 4;
      int jb = (c & 15) * 16;
      const unsigned char* gp = (const unsigned char*)(Bp + (size_t)r*K) + (jb ^ ((r&15)<<4));
      gld_lds16(gp, sB + (size_t)(j*256 + w*64)*16);
    }
  };
  stageB(sB0, 0);
  __syncthreads();

  bf16x8 af[4][2];
  #pragma unroll
  for(int kk=0;kk<4;++kk){
    int cb = kk*64 + (l>>4)*16;
    #pragma unroll
    for(int i=0;i<2;++i){
      int r = wr*32 + i*16 + (l&15);
      af[kk][i] = *reinterpret_cast<const bf16x8*>(sA + (size_t)r*ROWB + (cb ^ ((r&15)<<4)));
    }
  }

  f32x4 acc[SL][2][2];
  #pragma unroll
  for(int s=0;s<SL;++s)
    #pragma unroll
    for(int jc=0;jc<2;++jc)
      #pragma unroll
      for(int i=0;i<2;++i) acc[s][jc][i] = (f32x4){0.f,0.f,0.f,0.f};

  unsigned char* bufs[2] = {sB0, sB1};
  int cur = 0;
  #pragma unroll
  for(int s=0; s<SL; ++s){
    if(s+1 < SL) stageB(bufs[cur^1], s+1);
    #pragma unroll
    for(int kk=0;kk<4;++kk){
      int cb = kk*64 + (l>>4)*16;
      bf16x8 bfr[2];
      #pragma unroll
      for(int jc=0;jc<2;++jc){
        int cN = wc*32 + jc*16 + (l&15);
        bfr[jc] = *reinterpret_cast<const bf16x8*>(bufs[cur] + (size_t)cN*ROWB + (cb ^ ((cN&15)<<4)));
      }
      #pragma unroll
      for(int jc=0;jc<2;++jc)
        #pragma unroll
        for(int i=0;i<2;++i)
          acc[s][jc][i] = __builtin_amdgcn_mfma_f32_16x16x32_bf16(bfr[jc], af[kk][i], acc[s][jc][i], 0, 0, 0);
    }
    __syncthreads();
    cur ^= 1;
  }

  // predicated packed stores: skip empty (node,rel) slices when cntKeys given
  #pragma unroll
  for(int s=0;s<SL;++s){
    #pragma unroll
    for(int i=0;i<2;++i){
      int node = row0 + wr*32 + i*16 + (l&15);
      bool wr_ok = (node < M);
      if(wr_ok && cntKeys) wr_ok = (cntKeys[node*NREL + s] != 0);
      if(wr_ok){
        #pragma unroll
        for(int jc=0;jc<2;++jc){
          int c0 = s*64 + wc*32 + jc*16 + (l>>4)*4;
          uint2 v = pk4(acc[s][jc][i][0], acc[s][jc][i][1], acc[s][jc][i][2], acc[s][jc][i][3]);
          *(uint2*)(C + (size_t)node*ldc + c0) = v;
        }
      }
    }
  }
}

__global__ __launch_bounds__(256) void gemmMM_k(
    const ushortT* __restrict__ A1, const ushortT* __restrict__ BT1,
    ushortT* __restrict__ C1, int ldc1, int M1, int nt1, const int* __restrict__ cnt1,
    const ushortT* __restrict__ A2, const ushortT* __restrict__ BT2,
    ushortT* __restrict__ C2, int ldc2, int M2)
{
  __shared__ alignas(16) unsigned char sA[64*256];
  __shared__ alignas(16) unsigned char sB0[64*256];
  __shared__ alignas(16) unsigned char sB1[64*256];
  int bx = blockIdx.x;
  if(bx < nt1) gemmM_body<NREL>(A1, BT1, C1, ldc1, M1, bx, cnt1, sA, sB0, sB1);
  else         gemmM_body<1>(A2, BT2, C2, ldc2, M2, bx - nt1, nullptr, sA, sB0, sB1);
}

// ---------------- bf16 MFMA GEMM: BM=64, dbuf K-loop (layer-1 + fallback) ----------------

template<int BM, int BN, bool OUTBF, bool RELU>
__global__ __launch_bounds__(256) void gemm2v_k(
    const ushortT* __restrict__ A0, int lda0,
    const ushortT* __restrict__ A1, int lda1, int KSPLIT,
    const ushortT* __restrict__ BT, int K,
    const float* __restrict__ bias,
    void* __restrict__ Cv, int ldc, int M)
{
  constexpr int WGC = (BN>=128)? 2 : 1;
  constexpr int WGR = 4/WGC;
  constexpr int FR  = BM/(16*WGR);
  constexpr int FC  = BN/(16*WGC);
  constexpr int ACH = BM*8;
  constexpr int BCH = BN*8;
  __shared__ alignas(16) unsigned char sA[2][BM*128];
  __shared__ alignas(16) unsigned char sB[2][BN*128];

  const int tid = threadIdx.x;
  const int w = tid >> 6, l = tid & 63;
  const int wr = w / WGC, wc = w % WGC;
  const int row0 = blockIdx.y * BM;
  const int col0 = blockIdx.x * BN;
  const ushortT* BTp = BT + (size_t)col0 * K;

  f32x4 acc[FR][FC];
  #pragma unroll
  for(int i=0;i<FR;++i)
    #pragma unroll
    for(int j=0;j<FC;++j) acc[i][j] = (f32x4){0.f,0.f,0.f,0.f};

  auto stage = [&](int buf, int k0){
    const ushortT* Ab = (k0 < KSPLIT) ? A0 : A1;
    const int ldab    = (k0 < KSPLIT) ? lda0 : lda1;
    const int kc      = (k0 < KSPLIT) ? k0 : (k0 - KSPLIT);
    #pragma unroll
    for(int j=0;j<ACH/256;++j){
      int c = j*256 + tid;
      int r = c >> 3;
      int jb = (c & 7) * 16;
      int grow = row0 + r; grow = (grow < M) ? grow : (M-1);
      const unsigned char* gp = (const unsigned char*)(Ab + (size_t)grow*ldab + kc) + (jb ^ ((r&7)<<4));
      gld_lds16(gp, &sA[buf][(j*256 + w*64)*16]);
    }
    #pragma unroll
    for(int j=0;j<BCH/256;++j){
      int c = j*256 + tid;
      int r = c >> 3;
      int jb = (c & 7) * 16;
      const unsigned char* gp = (const unsigned char*)(BTp + (size_t)r*K + k0) + (jb ^ ((r&7)<<4));
      gld_lds16(gp, &sB[buf][(j*256 + w*64)*16]);
    }
  };

  const int NT = K >> 6;
  stage(0, 0);
  __syncthreads();
  int cur = 0;
  for(int t=0; t<NT; ++t){
    if(t+1 < NT) stage(cur^1, (t+1)<<6);
    #pragma unroll
    for(int kk=0;kk<2;++kk){
      const int cb = kk*64 + (l>>4)*16;
      bf16x8 af[FR], bfr[FC];
      #pragma unroll
      for(int i=0;i<FR;++i){
        int r = wr*(16*FR) + i*16 + (l&15);
        af[i] = *reinterpret_cast<const bf16x8*>(&sA[cur][r*128 + (cb ^ ((r&7)<<4))]);
      }
      #pragma unroll
      for(int j=0;j<FC;++j){
        int c = wc*(16*FC) + j*16 + (l&15);
        bfr[j] = *reinterpret_cast<const bf16x8*>(&sB[cur][c*128 + (cb ^ ((c&7)<<4))]);
      }
      #pragma unroll
      for(int i=0;i<FR;++i)
        #pragma unroll
        for(int j=0;j<FC;++j)
          acc[i][j] = __builtin_amdgcn_mfma_f32_16x16x32_bf16(af[i], bfr[j], acc[i][j], 0, 0, 0);
    }
    __syncthreads();
    cur ^= 1;
  }
  #pragma unroll
  for(int i=0;i<FR;++i){
    #pragma unroll
    for(int rr=0;rr<4;++rr){
      int grow = row0 + wr*(16*FR) + i*16 + (l>>4)*4 + rr;
      if(grow >= M) continue;
      #pragma unroll
      for(int j=0;j<FC;++j){
        int col = col0 + wc*(16*FC) + j*16 + (l&15);
        float v = acc[i][j][rr];
        if(bias) v += bias[col];
        if(RELU) v = fmaxf(v, 0.f);
        if(OUTBF) ((ushortT*)Cv)[(size_t)grow*ldc + col] = f2bf(v);
        else      ((float*)Cv)[(size_t)grow*ldc + col] = v;
      }
    }
  }
}

// ---------------- host ----------------

extern "C" void kernel_launch(void* const* d_in, const int* in_sizes, int n_in,
                              void* d_out, int out_size, void* d_ws, size_t ws_size,
                              hipStream_t stream){
  const float* x_user   = (const float*)d_in[0];
  const float* x_item   = (const float*)d_in[1];
  const int*   ei       = (const int*)d_in[2];
  const int*   et       = (const int*)d_in[3];
  const float* W1_ui    = (const float*)d_in[4];
  const float* root1_ui = (const float*)d_in[5];
  const float* b1_ui    = (const float*)d_in[6];
  const float* W1_iu    = (const float*)d_in[7];
  const float* root1_iu = (const float*)d_in[8];
  const float* b1_iu    = (const float*)d_in[9];
  const float* W2_ui    = (const float*)d_in[10];
  const float* root2_ui = (const float*)d_in[11];
  const float* b2_ui    = (const float*)d_in[12];
  const float* W2_iu    = (const float*)d_in[13];
  const float* root2_iu = (const float*)d_in[14];
  const float* b2_iu    = (const float*)d_in[15];
  const int E = in_sizes[3];
  const int* src = ei;
  const int* dst = ei + E;
  float* out = (float*)d_out;

  const int NI5 = NITEMS*NREL, NU5 = NUSERS*NREL;
  const int NK5 = NI5 + NU5;

  uint8_t* ws = (uint8_t*)d_ws;
  size_t o = 0;
  auto alloc = [&](size_t bytes){ size_t r = o; o = align256(o + bytes); return r; };
  int* cnt  = (int*)(ws + alloc((size_t)NK5*4));
  int* off  = (int*)(ws + alloc((size_t)(NK5+1)*4));
  int2* rank= (int2*)(ws + alloc((size_t)E*8));
  int* adj  = (int*)(ws + alloc((size_t)2*E*4));
  int* btot = (int*)(ws + alloc(1024*4));
  int* boff = (int*)(ws + alloc(1024*4));
  ushortT* xu_bf = (ushortT*)(ws + alloc((size_t)NUSERS*UDIM*2));
  ushortT* xi_bf = (ushortT*)(ws + alloc((size_t)NITEMS*UDIM*2));
  ushortT* h1u   = (ushortT*)(ws + alloc((size_t)NUSERS*HID*2));
  ushortT* h1i   = (ushortT*)(ws + alloc((size_t)NITEMS*HID*2));
  ushortT* BT1ui = (ushortT*)(ws + alloc((size_t)HID*(6*UDIM)*2));
  ushortT* BT1iu = (ushortT*)(ws + alloc((size_t)HID*(6*UDIM)*2));
  ushortT* BTm2ui = (ushortT*)(ws + alloc((size_t)NREL*ODIM*HID*2));
  ushortT* BTm2iu = (ushortT*)(ws + alloc((size_t)NREL*ODIM*HID*2));
  ushortT* BTr2ui = (ushortT*)(ws + alloc((size_t)ODIM*HID*2));
  ushortT* BTr2iu = (ushortT*)(ws + alloc((size_t)ODIM*HID*2));
  ushortT* BT2ui = (ushortT*)(ws + alloc((size_t)ODIM*(6*HID)*2));   // M-fallback
  ushortT* BT2iu = (ushortT*)(ws + alloc((size_t)ODIM*(6*HID)*2));
  size_t bigoff = o;
  size_t avail = (ws_size > bigoff)? (ws_size - bigoff) : 0;
  uint8_t* big = ws + bigoff;

  const int* off_i = off;
  const int* off_u = off + NI5;
  const int* cnt_i = cnt;
  const int* cnt_u = cnt + NI5;

  size_t needH = align256((size_t)NUSERS*NREL*ODIM*2) + align256((size_t)NITEMS*ODIM*2);
  bool useH = (avail >= needH + 4096);

  // ---- CSR build (combined; count records ranks, scatter is atomic-free) ----
  hipMemsetAsync(cnt, 0, (size_t)NK5*4, stream);
  int eb = (E+255)/256;
  count_edges_k<<<eb,256,0,stream>>>(src,dst,et,E,cnt,rank);
  int nb = (NK5+2047)/2048;
  scan_s1f<<<nb,256,0,stream>>>(cnt, NK5, btot);
  scan_s2<<<1,1024,0,stream>>>(btot, nb, boff, off+NK5);
  scan_s3f<<<nb,256,0,stream>>>(cnt, NK5, boff, off);
  scatter_k<<<eb,256,0,stream>>>(src,dst,et,E,off,rank,adj);

  // ---- dtype prep ----
  {
    int n4u = NUSERS*UDIM/4, n4i = NITEMS*UDIM/4;
    f2bf4b_k<<<(n4u+n4i+255)/256,256,0,stream>>>(
        (const float4*)x_user, n4u, (const float4*)x_item, n4i,
        (uint2*)xu_bf, (uint2*)xi_bf);
  }
  prep_bt_k<<<(HID*6*UDIM+255)/256,256,0,stream>>>(root1_ui, W1_ui, BT1ui, UDIM, HID);
  prep_bt_k<<<(HID*6*UDIM+255)/256,256,0,stream>>>(root1_iu, W1_iu, BT1iu, UDIM, HID);
  if(useH){
    int tot = NREL*ODIM*HID;
    prep_w_k<<<(tot+255)/256,256,0,stream>>>(W2_ui, BTm2ui, HID, ODIM, tot);
    prep_w_k<<<(tot+255)/256,256,0,stream>>>(W2_iu, BTm2iu, HID, ODIM, tot);
    prep_r_k<<<(ODIM*HID+255)/256,256,0,stream>>>(root2_ui, BTr2ui, HID, ODIM);
    prep_r_k<<<(ODIM*HID+255)/256,256,0,stream>>>(root2_iu, BTr2iu, HID, ODIM);
  } else {
    prep_bt_k<<<(ODIM*6*HID+255)/256,256,0,stream>>>(root2_ui, W2_ui, BT2ui, HID, ODIM);
    prep_bt_k<<<(ODIM*6*HID+255)/256,256,0,stream>>>(root2_iu, W2_iu, BT2iu, HID, ODIM);
  }

  // ---- layer 1: M-scheme agg (no-shuffle) + gemm2v BN=64 (32KB LDS -> 5 blocks/CU) ----
  {
    ushortT* Mbuf = (ushortT*)big;
    long long c1 = (long long)(avail / ((size_t)NREL*UDIM*2));
    int CH = (int)(c1 > 65536 ? 65536 : c1); CH &= ~127; if(CH < 128) CH = 128;
    for(int lo=0; lo<NITEMS; lo+=CH){
      int cn = imin(CH, NITEMS-lo);
      agg_m64_k<<<(cn+15)/16,256,0,stream>>>(xu_bf, adj, off_i + lo*NREL, Mbuf, cn);
      gemm2v_k<64,64,true,true><<<dim3(2,(cn+63)/64),256,0,stream>>>(
          xi_bf + (size_t)lo*UDIM, UDIM, Mbuf, NREL*UDIM, UDIM,
          BT1ui, 6*UDIM, b1_ui, h1i + (size_t)lo*HID, HID, cn);
    }
    for(int lo=0; lo<NUSERS; lo+=CH){
      int cn = imin(CH, NUSERS-lo);
      agg_m64_k<<<(cn+15)/16,256,0,stream>>>(xi_bf, adj, off_u + lo*NREL, Mbuf, cn);
      gemm2v_k<64,64,true,true><<<dim3(2,(cn+63)/64),256,0,stream>>>(
          xu_bf + (size_t)lo*UDIM, UDIM, Mbuf, NREL*UDIM, UDIM,
          BT1iu, 6*UDIM, b1_iu, h1u + (size_t)lo*HID, HID, cn);
    }
  }

  // ---- layer 2: phased H-scheme, msg+root merged per phase, msg stores predicated ----
  float* user2 = out;
  float* item2 = out + (size_t)NUSERS*ODIM;
  int ntU = (NUSERS+63)/64, ntI = (NITEMS+63)/64;
  if(useH){
    // phase A: msg user->item (SL5 over h1u, skip cnt_u==0 slices) + root item, then item agg
    ushortT* Hmsg_u  = (ushortT*)big;
    ushortT* Hroot_i = (ushortT*)(big + align256((size_t)NUSERS*NREL*ODIM*2));
    gemmMM_k<<<ntU+ntI,256,0,stream>>>(h1u, BTm2ui, Hmsg_u, NREL*ODIM, NUSERS, ntU, cnt_u,
                                       h1i, BTr2ui, Hroot_i, ODIM, NITEMS);
    agg_h_k<<<(NITEMS+15)/16,256,0,stream>>>(Hmsg_u, NREL*ODIM, Hroot_i, ODIM,
        adj, off_i, b2_ui, item2, NITEMS);
    // phase B: msg item->user (skip cnt_i==0 slices) + root user (overlay), then user agg
    ushortT* Hmsg_i  = (ushortT*)big;
    ushortT* Hroot_u = (ushortT*)(big + align256((size_t)NITEMS*NREL*ODIM*2));
    gemmMM_k<<<ntI+ntU,256,0,stream>>>(h1i, BTm2iu, Hmsg_i, NREL*ODIM, NITEMS, ntI, cnt_i,
                                       h1u, BTr2iu, Hroot_u, ODIM, NUSERS);
    agg_h_k<<<(NUSERS+15)/16,256,0,stream>>>(Hmsg_i, NREL*ODIM, Hroot_u, ODIM,
        adj, off_u, b2_iu, user2, NUSERS);
  } else {
    // fallback M-scheme
    ushortT* Mbuf = (ushortT*)big;
    long long c2 = (long long)(avail / ((size_t)6*HID*2));
    int CH = (int)(c2 > NUSERS ? NUSERS : c2); CH &= ~127; if(CH < 128) CH = 128;
    for(int lo=0; lo<NITEMS; lo+=CH){
      int cn = imin(CH, NITEMS-lo);
      agg_m_k<HID><<<(cn+3)/4,256,0,stream>>>(h1u, h1i, adj, off_i, Mbuf, lo, cn);
      gemm2v_k<64,64,false,false><<<dim3(1,(cn+63)/64),256,0,stream>>>(
          Mbuf, 6*HID, Mbuf, 6*HID, 6*HID, BT2ui, 6*HID, b2_ui, item2 + (size_t)lo*ODIM, ODIM, cn);
    }
    for(int lo=0; lo<NUSERS; lo+=CH){
      int cn = imin(CH, NUSERS-lo);
      agg_m_k<HID><<<(cn+3)/4,256,0,stream>>>(h1i, h1u, adj, off_u, Mbuf, lo, cn);
      gemm2v_k<64,64,false,false><<<dim3(1,(cn+63)/64),256,0,stream>>>(
          Mbuf, 6*HID, Mbuf, 6*HID, 6*HID, BT2iu, 6*HID, b2_iu, user2 + (size_t)lo*ODIM, ODIM, cn);
    }
  }
}

// Round 20
// 499.373 us; speedup vs baseline: 1.1207x; 1.0327x over previous
//
#include <hip/hip_runtime.h>
#include <hip/hip_bf16.h>
#include <cstdint>
#include <cstddef>

#define NUSERS 200000
#define NITEMS 100000
#define UDIM 64
#define HID 128
#define ODIM 64
#define NREL 5

typedef unsigned short ushortT;
typedef __bf16 bf16x8 __attribute__((ext_vector_type(8)));
typedef __bf16 bf16x4p __attribute__((ext_vector_type(4)));
typedef float f32x4 __attribute__((ext_vector_type(4)));

static inline size_t align256(size_t x){ return (x + 255) & ~(size_t)255; }
static inline int imin(int a,int b){ return a<b?a:b; }

__device__ __forceinline__ unsigned short f2bf(float f){
  unsigned int u = __builtin_bit_cast(unsigned int, f);
  unsigned int r = (u + 0x7fffu + ((u>>16)&1u)) >> 16;   // RNE
  return (unsigned short)r;
}
__device__ __forceinline__ float b2f(unsigned short u){
  return __builtin_bit_cast(float, ((unsigned int)u)<<16);
}
__device__ __forceinline__ float blo(unsigned u){ return b2f((unsigned short)(u & 0xffff)); }
__device__ __forceinline__ float bhi(unsigned u){ return b2f((unsigned short)(u >> 16)); }
__device__ __forceinline__ uint2 pk4(float a, float b, float c, float d){
  bf16x4p t; t[0]=(__bf16)a; t[1]=(__bf16)b; t[2]=(__bf16)c; t[3]=(__bf16)d;
  return __builtin_bit_cast(uint2, t);
}
__device__ __forceinline__ void gld_lds16(const void* g, void* s){
  __builtin_amdgcn_global_load_lds((const __attribute__((address_space(1))) void*)g,
                                   (__attribute__((address_space(3))) void*)s, 16, 0, 0);
}

// ---------------- fused pre-pass: CSR count (+rank record) || fp32->bf16 convert ----------------
// segments: [0, ebC) edge counting; [ebC, ebC+nf) feature conversion.

__device__ __forceinline__ void d_f2bf4(const float4* a, uint2* b, int idx){
  float4 v = a[idx];
  uint2 o;
  o.x = (unsigned)f2bf(v.x) | ((unsigned)f2bf(v.y)<<16);
  o.y = (unsigned)f2bf(v.z) | ((unsigned)f2bf(v.w)<<16);
  b[idx] = o;
}

__global__ __launch_bounds__(256) void pre_k(
    const int* __restrict__ src, const int* __restrict__ dst,
    const int* __restrict__ et, int E,
    int* __restrict__ cnt, int2* __restrict__ rank, int ebC,
    const float4* __restrict__ a1, int n1,
    const float4* __restrict__ a2, int n2,
    uint2* __restrict__ b1, uint2* __restrict__ b2)
{
  int bx = blockIdx.x;
  if(bx < ebC){
    int e = bx*256 + threadIdx.x;
    if(e < E){
      int t = et[e];
      int r1 = atomicAdd(&cnt[dst[e]*NREL + t], 1);
      int r2 = atomicAdd(&cnt[NITEMS*NREL + src[e]*NREL + t], 1);
      rank[e] = make_int2(r1, r2);
    }
    return;
  }
  int i = (bx - ebC)*256 + threadIdx.x;
  if(i < n1)            d_f2bf4(a1, b1, i);
  else if(i < n1+n2)    d_f2bf4(a2, b2, i - n1);
}

// ---------------- scans ----------------

__global__ __launch_bounds__(256) void scan_s1f(const int* __restrict__ c, int n, int* __restrict__ btot){
  int t = threadIdx.x;
  int base = blockIdx.x*2048 + t*8;
  int s = 0;
  #pragma unroll
  for(int j=0;j<8;++j){ int i = base+j; if(i<n) s += c[i]; }
  __shared__ int red[256];
  red[t] = s; __syncthreads();
  for(int o=128;o>0;o>>=1){ if(t<o) red[t]+=red[t+o]; __syncthreads(); }
  if(t==0) btot[blockIdx.x] = red[0];
}

__global__ __launch_bounds__(1024) void scan_s2(const int* __restrict__ btot, int nb,
                                                int* __restrict__ boff, int* __restrict__ total_out){
  __shared__ int sh[1024];
  int t = threadIdx.x;
  int v = (t<nb)? btot[t] : 0;
  sh[t] = v; __syncthreads();
  for(int o=1;o<1024;o<<=1){
    int add = (t>=o)? sh[t-o] : 0;
    __syncthreads();
    sh[t] += add;
    __syncthreads();
  }
  if(t<nb) boff[t] = sh[t]-v;
  if(t==1023) *total_out = sh[1023];
}

__global__ __launch_bounds__(256) void scan_s3f(const int* __restrict__ c, int n,
                                                const int* __restrict__ boff,
                                                int* __restrict__ off){
  int t = threadIdx.x, b = blockIdx.x;
  int base = b*2048 + t*8;
  int pre[8]; int s = 0;
  #pragma unroll
  for(int j=0;j<8;++j){
    int i = base+j; int d = (i<n)? c[i] : 0;
    pre[j] = s; s += d;
  }
  __shared__ int sh[256];
  sh[t] = s; __syncthreads();
  int inc = s;
  for(int o=1;o<256;o<<=1){
    int add = (t>=o)? sh[t-o] : 0;
    __syncthreads();
    sh[t] += add;
    __syncthreads();
  }
  int texcl = sh[t] - inc;
  int bo = boff[b];
  #pragma unroll
  for(int j=0;j<8;++j){
    int i = base+j;
    if(i<n) off[i] = bo + texcl + pre[j];
  }
}

// ---------------- fused aux pass: atomic-free scatter || 6 weight preps ----------------
// prep bodies (device):

__device__ __forceinline__ void d_prep_bt(const float* root, const float* W,
                                          ushortT* BT, int Din, int Dout, int idx){
  int K = 6*Din;
  int n = idx / K, k = idx % K;
  float v = (k < Din) ? root[(size_t)k*Dout + n] : W[(size_t)(k-Din)*Dout + n];
  BT[idx] = f2bf(v);
}
__device__ __forceinline__ void d_prep_w(const float* W, ushortT* BT, int Kdim, int C, int idx){
  int n = idx / Kdim, k = idx % Kdim;
  int r = n / C, c = n % C;
  BT[idx] = f2bf(W[((size_t)r*Kdim + k)*C + c]);
}
__device__ __forceinline__ void d_prep_r(const float* root, ushortT* BT, int Kdim, int C, int idx){
  int n = idx / Kdim, k = idx % Kdim;
  BT[idx] = f2bf(root[(size_t)k*C + n]);
}

// segment sizes (blocks of 256): BT1 = HID*6*UDIM/256 = 192 each; W2 = NREL*ODIM*HID/256 = 160 each;
// R2 = ODIM*HID/256 = 32 each. All exact multiples of 256 elements.
__global__ __launch_bounds__(256) void aux_k(
    const int* __restrict__ src, const int* __restrict__ dst,
    const int* __restrict__ et, int E,
    const int* __restrict__ off, const int2* __restrict__ rank,
    int* __restrict__ adj, int eb,
    const float* __restrict__ root1_ui, const float* __restrict__ W1_ui, ushortT* __restrict__ BT1ui,
    const float* __restrict__ root1_iu, const float* __restrict__ W1_iu, ushortT* __restrict__ BT1iu,
    const float* __restrict__ W2_ui, ushortT* __restrict__ BTm2ui,
    const float* __restrict__ W2_iu, ushortT* __restrict__ BTm2iu,
    const float* __restrict__ root2_ui, ushortT* __restrict__ BTr2ui,
    const float* __restrict__ root2_iu, ushortT* __restrict__ BTr2iu)
{
  int bx = blockIdx.x;
  int tid = threadIdx.x;
  if(bx < eb){
    int e = bx*256 + tid;
    if(e < E){
      int s = src[e], d = dst[e], t = et[e];
      int2 r = rank[e];
      adj[off[d*NREL + t] + r.x] = s;
      adj[off[NITEMS*NREL + s*NREL + t] + r.y] = d;
    }
    return;
  }
  bx -= eb;
  if(bx < 192){ d_prep_bt(root1_ui, W1_ui, BT1ui, UDIM, HID, bx*256 + tid); return; }
  bx -= 192;
  if(bx < 192){ d_prep_bt(root1_iu, W1_iu, BT1iu, UDIM, HID, bx*256 + tid); return; }
  bx -= 192;
  if(bx < 160){ d_prep_w(W2_ui, BTm2ui, HID, ODIM, bx*256 + tid); return; }
  bx -= 160;
  if(bx < 160){ d_prep_w(W2_iu, BTm2iu, HID, ODIM, bx*256 + tid); return; }
  bx -= 160;
  if(bx < 32){ d_prep_r(root2_ui, BTr2ui, HID, ODIM, bx*256 + tid); return; }
  bx -= 32;
  d_prep_r(root2_iu, BTr2iu, HID, ODIM, bx*256 + tid);
}

// standalone prep (fallback tier only)
__global__ void prep_bt_k(const float* __restrict__ root, const float* __restrict__ W,
                          ushortT* __restrict__ BT, int Din, int Dout){
  int K = 6*Din;
  int idx = blockIdx.x*blockDim.x + threadIdx.x;
  if(idx >= Dout*K) return;
  d_prep_bt(root, W, BT, Din, Dout, idx);
}

// ---------------- layer-1 aggregation (D=64): 16-lane group per node ----------------

__global__ __launch_bounds__(256) void agg_m64_k(const ushortT* __restrict__ xsrc,
    const int* __restrict__ adj, const int* __restrict__ off5,
    ushortT* __restrict__ Mbuf, int cn)
{
  int gid = blockIdx.x*blockDim.x + threadIdx.x;
  int wid = gid >> 4;
  int sub = gid & 15;
  if(wid >= cn) return;
  const int* op = off5 + wid*NREL;
  int offs[6];
  #pragma unroll
  for(int r=0;r<6;++r) offs[r] = op[r];
  ushortT* mp = Mbuf + (size_t)wid*(NREL*UDIM) + sub*4;
  const ushortT* xp = xsrc + sub*4;
  #pragma unroll
  for(int r=0;r<NREL;++r){
    int e0 = offs[r], e1 = offs[r+1];
    uint2 o = {0u, 0u};
    if(e1 > e0){
      float s0=0.f, s1=0.f, s2=0.f, s3=0.f;
      for(int e=e0; e<e1; ++e){
        int p = adj[e];
        uint2 u = *(const uint2*)(xp + (size_t)p*UDIM);
        s0 += blo(u.x); s1 += bhi(u.x); s2 += blo(u.y); s3 += bhi(u.y);
      }
      float scv = 1.f/(float)(e1-e0);
      o = pk4(s0*scv, s1*scv, s2*scv, s3*scv);
    }
    *(uint2*)(mp + r*UDIM) = o;
  }
}

// ---------------- layer-2 H aggregation: 16-lane group per node, segmented ----------------

__global__ __launch_bounds__(256) void agg_h_k(const ushortT* __restrict__ msg, int msgStride,
    const ushortT* __restrict__ root, int rootStride,
    const int* __restrict__ adj, const int* __restrict__ off5,
    const float* __restrict__ bias, float* __restrict__ outp, int n)
{
  int gid = blockIdx.x*blockDim.x + threadIdx.x;
  int node = gid >> 4;
  int sub = gid & 15;
  if(node >= n) return;
  const int* op = off5 + node*NREL;
  int offs[6];
  #pragma unroll
  for(int r=0;r<6;++r) offs[r] = op[r];
  float a0=0.f,a1=0.f,a2=0.f,a3=0.f;
  #pragma unroll
  for(int r=0;r<NREL;++r){
    int e0 = offs[r], e1 = offs[r+1];
    if(e1 > e0){
      const ushortT* mslice = msg + r*ODIM + sub*4;
      float s0=0.f,s1=0.f,s2=0.f,s3=0.f;
      for(int e=e0; e<e1; ++e){
        int p = adj[e];
        uint2 u = *(const uint2*)(mslice + (size_t)p*msgStride);
        s0 += blo(u.x); s1 += bhi(u.x); s2 += blo(u.y); s3 += bhi(u.y);
      }
      float scv = 1.f/(float)(e1-e0);
      a0 += s0*scv; a1 += s1*scv; a2 += s2*scv; a3 += s3*scv;
    }
  }
  uint2 rt = *(const uint2*)(root + (size_t)node*rootStride + sub*4);
  float4 bv = *(const float4*)(bias + sub*4);
  float4 o;
  o.x = a0 + blo(rt.x) + bv.x;
  o.y = a1 + bhi(rt.x) + bv.y;
  o.z = a2 + blo(rt.y) + bv.z;
  o.w = a3 + bhi(rt.y) + bv.w;
  *(float4*)(outp + (size_t)node*ODIM + sub*4) = o;
}

// ---------------- fallback M-scheme agg (layer 2, only if ws too small) ----------------

template<int D>
__global__ __launch_bounds__(256) void agg_m_k(const ushortT* __restrict__ xsrc,
    const ushortT* __restrict__ xdst, const int* __restrict__ adj,
    const int* __restrict__ off5, ushortT* __restrict__ Mbuf, int lo, int cn)
{
  int wid  = (int)((blockIdx.x*(size_t)blockDim.x + threadIdx.x) >> 6);
  int lane = threadIdx.x & 63;
  if(wid >= cn) return;
  int node = lo + wid;
  constexpr int V = D/64;
  ushortT* mp = Mbuf + (size_t)wid*(6*D);
  if(V==2) *(unsigned*)(mp + lane*2) = *(const unsigned*)(xdst + (size_t)node*D + lane*2);
  else     mp[lane] = xdst[(size_t)node*D + lane];
  #pragma unroll
  for(int r=0;r<NREL;++r){
    int base = node*NREL + r;
    int e0 = off5[base], e1 = off5[base+1];
    float s0 = 0.f, s1 = 0.f;
    for(int e=e0; e<e1; ++e){
      int p = adj[e];
      if(V==2){
        unsigned u = *(const unsigned*)(xsrc + (size_t)p*D + lane*2);
        s0 += blo(u); s1 += bhi(u);
      } else {
        s0 += b2f(xsrc[(size_t)p*D + lane]);
      }
    }
    int c = e1 - e0;
    float sc = 1.f/(float)(c>0? c:1);
    if(V==2){
      unsigned o = (unsigned)f2bf(s0*sc) | ((unsigned)f2bf(s1*sc)<<16);
      *(unsigned*)(mp + D + r*D + lane*2) = o;
    } else {
      mp[D + r*D + lane] = f2bf(s0*sc);
    }
  }
}

// ---------------- A-resident multi-slice GEMM body (K=128), operand-swapped ----------------

template<int SL>
__device__ __forceinline__ void gemmM_body(
    const ushortT* __restrict__ A, const ushortT* __restrict__ BT,
    ushortT* __restrict__ C, int ldc, int M, int bx,
    const int* __restrict__ cntKeys,
    unsigned char* sA, unsigned char* sB0, unsigned char* sB1)
{
  constexpr int K = 128, ROWB = 256;
  const int tid = threadIdx.x;
  const int w = tid >> 6, l = tid & 63;
  const int wr = w >> 1, wc = w & 1;
  const int row0 = bx * 64;

  #pragma unroll
  for(int j=0;j<4;++j){
    int c = j*256 + tid;
    int r = c >> 4;
    int jb = (c & 15) * 16;
    int grow = row0 + r; grow = (grow < M) ? grow : (M-1);
    const unsigned char* gp = (const unsigned char*)(A + (size_t)grow*K) + (jb ^ ((r&15)<<4));
    gld_lds16(gp, sA + (size_t)(j*256 + w*64)*16);
  }
  auto stageB = [&](unsigned char* sB, int s){
    const ushortT* Bp = BT + (size_t)s*64*K;
    #pragma unroll
    for(int j=0;j<4;++j){
      int c = j*256 + tid;
      int r = c >> 4;
      int jb = (c & 15) * 16;
      const unsigned char* gp = (const unsigned char*)(Bp + (size_t)r*K) + (jb ^ ((r&15)<<4));
      gld_lds16(gp, sB + (size_t)(j*256 + w*64)*16);
    }
  };
  stageB(sB0, 0);
  __syncthreads();

  bf16x8 af[4][2];
  #pragma unroll
  for(int kk=0;kk<4;++kk){
    int cb = kk*64 + (l>>4)*16;
    #pragma unroll
    for(int i=0;i<2;++i){
      int r = wr*32 + i*16 + (l&15);
      af[kk][i] = *reinterpret_cast<const bf16x8*>(sA + (size_t)r*ROWB + (cb ^ ((r&15)<<4)));
    }
  }

  f32x4 acc[SL][2][2];
  #pragma unroll
  for(int s=0;s<SL;++s)
    #pragma unroll
    for(int jc=0;jc<2;++jc)
      #pragma unroll
      for(int i=0;i<2;++i) acc[s][jc][i] = (f32x4){0.f,0.f,0.f,0.f};

  unsigned char* bufs[2] = {sB0, sB1};
  int cur = 0;
  #pragma unroll
  for(int s=0; s<SL; ++s){
    if(s+1 < SL) stageB(bufs[cur^1], s+1);
    #pragma unroll
    for(int kk=0;kk<4;++kk){
      int cb = kk*64 + (l>>4)*16;
      bf16x8 bfr[2];
      #pragma unroll
      for(int jc=0;jc<2;++jc){
        int cN = wc*32 + jc*16 + (l&15);
        bfr[jc] = *reinterpret_cast<const bf16x8*>(bufs[cur] + (size_t)cN*ROWB + (cb ^ ((cN&15)<<4)));
      }
      #pragma unroll
      for(int jc=0;jc<2;++jc)
        #pragma unroll
        for(int i=0;i<2;++i)
          acc[s][jc][i] = __builtin_amdgcn_mfma_f32_16x16x32_bf16(bfr[jc], af[kk][i], acc[s][jc][i], 0, 0, 0);
    }
    __syncthreads();
    cur ^= 1;
  }

  // predicated packed stores: skip empty (node,rel) slices when cntKeys given
  #pragma unroll
  for(int s=0;s<SL;++s){
    #pragma unroll
    for(int i=0;i<2;++i){
      int node = row0 + wr*32 + i*16 + (l&15);
      bool wr_ok = (node < M);
      if(wr_ok && cntKeys) wr_ok = (cntKeys[node*NREL + s] != 0);
      if(wr_ok){
        #pragma unroll
        for(int jc=0;jc<2;++jc){
          int c0 = s*64 + wc*32 + jc*16 + (l>>4)*4;
          uint2 v = pk4(acc[s][jc][i][0], acc[s][jc][i][1], acc[s][jc][i][2], acc[s][jc][i][3]);
          *(uint2*)(C + (size_t)node*ldc + c0) = v;
        }
      }
    }
  }
}

__global__ __launch_bounds__(256) void gemmMM_k(
    const ushortT* __restrict__ A1, const ushortT* __restrict__ BT1,
    ushortT* __restrict__ C1, int ldc1, int M1, int nt1, const int* __restrict__ cnt1,
    const ushortT* __restrict__ A2, const ushortT* __restrict__ BT2,
    ushortT* __restrict__ C2, int ldc2, int M2)
{
  __shared__ alignas(16) unsigned char sA[64*256];
  __shared__ alignas(16) unsigned char sB0[64*256];
  __shared__ alignas(16) unsigned char sB1[64*256];
  int bx = blockIdx.x;
  if(bx < nt1) gemmM_body<NREL>(A1, BT1, C1, ldc1, M1, bx, cnt1, sA, sB0, sB1);
  else         gemmM_body<1>(A2, BT2, C2, ldc2, M2, bx - nt1, nullptr, sA, sB0, sB1);
}

// ---------------- bf16 MFMA GEMM: BM=64, dbuf K-loop (layer-1 + fallback) ----------------

template<int BM, int BN, bool OUTBF, bool RELU>
__global__ __launch_bounds__(256) void gemm2v_k(
    const ushortT* __restrict__ A0, int lda0,
    const ushortT* __restrict__ A1, int lda1, int KSPLIT,
    const ushortT* __restrict__ BT, int K,
    const float* __restrict__ bias,
    void* __restrict__ Cv, int ldc, int M)
{
  constexpr int WGC = (BN>=128)? 2 : 1;
  constexpr int WGR = 4/WGC;
  constexpr int FR  = BM/(16*WGR);
  constexpr int FC  = BN/(16*WGC);
  constexpr int ACH = BM*8;
  constexpr int BCH = BN*8;
  __shared__ alignas(16) unsigned char sA[2][BM*128];
  __shared__ alignas(16) unsigned char sB[2][BN*128];

  const int tid = threadIdx.x;
  const int w = tid >> 6, l = tid & 63;
  const int wr = w / WGC, wc = w % WGC;
  const int row0 = blockIdx.y * BM;
  const int col0 = blockIdx.x * BN;
  const ushortT* BTp = BT + (size_t)col0 * K;

  f32x4 acc[FR][FC];
  #pragma unroll
  for(int i=0;i<FR;++i)
    #pragma unroll
    for(int j=0;j<FC;++j) acc[i][j] = (f32x4){0.f,0.f,0.f,0.f};

  auto stage = [&](int buf, int k0){
    const ushortT* Ab = (k0 < KSPLIT) ? A0 : A1;
    const int ldab    = (k0 < KSPLIT) ? lda0 : lda1;
    const int kc      = (k0 < KSPLIT) ? k0 : (k0 - KSPLIT);
    #pragma unroll
    for(int j=0;j<ACH/256;++j){
      int c = j*256 + tid;
      int r = c >> 3;
      int jb = (c & 7) * 16;
      int grow = row0 + r; grow = (grow < M) ? grow : (M-1);
      const unsigned char* gp = (const unsigned char*)(Ab + (size_t)grow*ldab + kc) + (jb ^ ((r&7)<<4));
      gld_lds16(gp, &sA[buf][(j*256 + w*64)*16]);
    }
    #pragma unroll
    for(int j=0;j<BCH/256;++j){
      int c = j*256 + tid;
      int r = c >> 3;
      int jb = (c & 7) * 16;
      const unsigned char* gp = (const unsigned char*)(BTp + (size_t)r*K + k0) + (jb ^ ((r&7)<<4));
      gld_lds16(gp, &sB[buf][(j*256 + w*64)*16]);
    }
  };

  const int NT = K >> 6;
  stage(0, 0);
  __syncthreads();
  int cur = 0;
  for(int t=0; t<NT; ++t){
    if(t+1 < NT) stage(cur^1, (t+1)<<6);
    #pragma unroll
    for(int kk=0;kk<2;++kk){
      const int cb = kk*64 + (l>>4)*16;
      bf16x8 af[FR], bfr[FC];
      #pragma unroll
      for(int i=0;i<FR;++i){
        int r = wr*(16*FR) + i*16 + (l&15);
        af[i] = *reinterpret_cast<const bf16x8*>(&sA[cur][r*128 + (cb ^ ((r&7)<<4))]);
      }
      #pragma unroll
      for(int j=0;j<FC;++j){
        int c = wc*(16*FC) + j*16 + (l&15);
        bfr[j] = *reinterpret_cast<const bf16x8*>(&sB[cur][c*128 + (cb ^ ((c&7)<<4))]);
      }
      #pragma unroll
      for(int i=0;i<FR;++i)
        #pragma unroll
        for(int j=0;j<FC;++j)
          acc[i][j] = __builtin_amdgcn_mfma_f32_16x16x32_bf16(af[i], bfr[j], acc[i][j], 0, 0, 0);
    }
    __syncthreads();
    cur ^= 1;
  }
  #pragma unroll
  for(int i=0;i<FR;++i){
    #pragma unroll
    for(int rr=0;rr<4;++rr){
      int grow = row0 + wr*(16*FR) + i*16 + (l>>4)*4 + rr;
      if(grow >= M) continue;
      #pragma unroll
      for(int j=0;j<FC;++j){
        int col = col0 + wc*(16*FC) + j*16 + (l&15);
        float v = acc[i][j][rr];
        if(bias) v += bias[col];
        if(RELU) v = fmaxf(v, 0.f);
        if(OUTBF) ((ushortT*)Cv)[(size_t)grow*ldc + col] = f2bf(v);
        else      ((float*)Cv)[(size_t)grow*ldc + col] = v;
      }
    }
  }
}

// ---------------- host ----------------

extern "C" void kernel_launch(void* const* d_in, const int* in_sizes, int n_in,
                              void* d_out, int out_size, void* d_ws, size_t ws_size,
                              hipStream_t stream){
  const float* x_user   = (const float*)d_in[0];
  const float* x_item   = (const float*)d_in[1];
  const int*   ei       = (const int*)d_in[2];
  const int*   et       = (const int*)d_in[3];
  const float* W1_ui    = (const float*)d_in[4];
  const float* root1_ui = (const float*)d_in[5];
  const float* b1_ui    = (const float*)d_in[6];
  const float* W1_iu    = (const float*)d_in[7];
  const float* root1_iu = (const float*)d_in[8];
  const float* b1_iu    = (const float*)d_in[9];
  const float* W2_ui    = (const float*)d_in[10];
  const float* root2_ui = (const float*)d_in[11];
  const float* b2_ui    = (const float*)d_in[12];
  const float* W2_iu    = (const float*)d_in[13];
  const float* root2_iu = (const float*)d_in[14];
  const float* b2_iu    = (const float*)d_in[15];
  const int E = in_sizes[3];
  const int* src = ei;
  const int* dst = ei + E;
  float* out = (float*)d_out;

  const int NI5 = NITEMS*NREL, NU5 = NUSERS*NREL;
  const int NK5 = NI5 + NU5;

  uint8_t* ws = (uint8_t*)d_ws;
  size_t o = 0;
  auto alloc = [&](size_t bytes){ size_t r = o; o = align256(o + bytes); return r; };
  int* cnt  = (int*)(ws + alloc((size_t)NK5*4));
  int* off  = (int*)(ws + alloc((size_t)(NK5+1)*4));
  int2* rank= (int2*)(ws + alloc((size_t)E*8));
  int* adj  = (int*)(ws + alloc((size_t)2*E*4));
  int* btot = (int*)(ws + alloc(1024*4));
  int* boff = (int*)(ws + alloc(1024*4));
  ushortT* xu_bf = (ushortT*)(ws + alloc((size_t)NUSERS*UDIM*2));
  ushortT* xi_bf = (ushortT*)(ws + alloc((size_t)NITEMS*UDIM*2));
  ushortT* h1u   = (ushortT*)(ws + alloc((size_t)NUSERS*HID*2));
  ushortT* h1i   = (ushortT*)(ws + alloc((size_t)NITEMS*HID*2));
  ushortT* BT1ui = (ushortT*)(ws + alloc((size_t)HID*(6*UDIM)*2));
  ushortT* BT1iu = (ushortT*)(ws + alloc((size_t)HID*(6*UDIM)*2));
  ushortT* BTm2ui = (ushortT*)(ws + alloc((size_t)NREL*ODIM*HID*2));
  ushortT* BTm2iu = (ushortT*)(ws + alloc((size_t)NREL*ODIM*HID*2));
  ushortT* BTr2ui = (ushortT*)(ws + alloc((size_t)ODIM*HID*2));
  ushortT* BTr2iu = (ushortT*)(ws + alloc((size_t)ODIM*HID*2));
  ushortT* BT2ui = (ushortT*)(ws + alloc((size_t)ODIM*(6*HID)*2));   // M-fallback
  ushortT* BT2iu = (ushortT*)(ws + alloc((size_t)ODIM*(6*HID)*2));
  size_t bigoff = o;
  size_t avail = (ws_size > bigoff)? (ws_size - bigoff) : 0;
  uint8_t* big = ws + bigoff;

  const int* off_i = off;
  const int* off_u = off + NI5;
  const int* cnt_i = cnt;
  const int* cnt_u = cnt + NI5;

  size_t needH = align256((size_t)NUSERS*NREL*ODIM*2) + align256((size_t)NITEMS*ODIM*2);
  bool useH = (avail >= needH + 4096);

  // ---- fused pre-pass: CSR count (+ranks) || bf16 conversion ----
  hipMemsetAsync(cnt, 0, (size_t)NK5*4, stream);
  int eb = (E+255)/256;
  int n4u = NUSERS*UDIM/4, n4i = NITEMS*UDIM/4;
  int nf = (n4u+n4i+255)/256;
  pre_k<<<eb+nf,256,0,stream>>>(src,dst,et,E,cnt,rank,eb,
      (const float4*)x_user, n4u, (const float4*)x_item, n4i,
      (uint2*)xu_bf, (uint2*)xi_bf);

  // ---- scans ----
  int nb = (NK5+2047)/2048;
  scan_s1f<<<nb,256,0,stream>>>(cnt, NK5, btot);
  scan_s2<<<1,1024,0,stream>>>(btot, nb, boff, off+NK5);
  scan_s3f<<<nb,256,0,stream>>>(cnt, NK5, boff, off);

  // ---- fused aux pass: atomic-free scatter || weight preps ----
  if(useH){
    aux_k<<<eb+192+192+160+160+32+32,256,0,stream>>>(
        src,dst,et,E, off,rank,adj, eb,
        root1_ui, W1_ui, BT1ui, root1_iu, W1_iu, BT1iu,
        W2_ui, BTm2ui, W2_iu, BTm2iu,
        root2_ui, BTr2ui, root2_iu, BTr2iu);
  } else {
    aux_k<<<eb+192+192+160+160+32+32,256,0,stream>>>(
        src,dst,et,E, off,rank,adj, eb,
        root1_ui, W1_ui, BT1ui, root1_iu, W1_iu, BT1iu,
        W2_ui, BTm2ui, W2_iu, BTm2iu,
        root2_ui, BTr2ui, root2_iu, BTr2iu);
    prep_bt_k<<<(ODIM*6*HID+255)/256,256,0,stream>>>(root2_ui, W2_ui, BT2ui, HID, ODIM);
    prep_bt_k<<<(ODIM*6*HID+255)/256,256,0,stream>>>(root2_iu, W2_iu, BT2iu, HID, ODIM);
  }

  // ---- layer 1: M-scheme agg (no-shuffle) + gemm2v BN=64 (32KB LDS -> 5 blocks/CU) ----
  {
    ushortT* Mbuf = (ushortT*)big;
    long long c1 = (long long)(avail / ((size_t)NREL*UDIM*2));
    int CH = (int)(c1 > 65536 ? 65536 : c1); CH &= ~127; if(CH < 128) CH = 128;
    for(int lo=0; lo<NITEMS; lo+=CH){
      int cn = imin(CH, NITEMS-lo);
      agg_m64_k<<<(cn+15)/16,256,0,stream>>>(xu_bf, adj, off_i + lo*NREL, Mbuf, cn);
      gemm2v_k<64,64,true,true><<<dim3(2,(cn+63)/64),256,0,stream>>>(
          xi_bf + (size_t)lo*UDIM, UDIM, Mbuf, NREL*UDIM, UDIM,
          BT1ui, 6*UDIM, b1_ui, h1i + (size_t)lo*HID, HID, cn);
    }
    for(int lo=0; lo<NUSERS; lo+=CH){
      int cn = imin(CH, NUSERS-lo);
      agg_m64_k<<<(cn+15)/16,256,0,stream>>>(xi_bf, adj, off_u + lo*NREL, Mbuf, cn);
      gemm2v_k<64,64,true,true><<<dim3(2,(cn+63)/64),256,0,stream>>>(
          xu_bf + (size_t)lo*UDIM, UDIM, Mbuf, NREL*UDIM, UDIM,
          BT1iu, 6*UDIM, b1_iu, h1u + (size_t)lo*HID, HID, cn);
    }
  }

  // ---- layer 2: phased H-scheme, msg+root merged per phase, msg stores predicated ----
  float* user2 = out;
  float* item2 = out + (size_t)NUSERS*ODIM;
  int ntU = (NUSERS+63)/64, ntI = (NITEMS+63)/64;
  if(useH){
    // phase A: msg user->item (SL5 over h1u, skip cnt_u==0 slices) + root item, then item agg
    ushortT* Hmsg_u  = (ushortT*)big;
    ushortT* Hroot_i = (ushortT*)(big + align256((size_t)NUSERS*NREL*ODIM*2));
    gemmMM_k<<<ntU+ntI,256,0,stream>>>(h1u, BTm2ui, Hmsg_u, NREL*ODIM, NUSERS, ntU, cnt_u,
                                       h1i, BTr2ui, Hroot_i, ODIM, NITEMS);
    agg_h_k<<<(NITEMS+15)/16,256,0,stream>>>(Hmsg_u, NREL*ODIM, Hroot_i, ODIM,
        adj, off_i, b2_ui, item2, NITEMS);
    // phase B: msg item->user (skip cnt_i==0 slices) + root user (overlay), then user agg
    ushortT* Hmsg_i  = (ushortT*)big;
    ushortT* Hroot_u = (ushortT*)(big + align256((size_t)NITEMS*NREL*ODIM*2));
    gemmMM_k<<<ntI+ntU,256,0,stream>>>(h1i, BTm2iu, Hmsg_i, NREL*ODIM, NITEMS, ntI, cnt_i,
                                       h1u, BTr2iu, Hroot_u, ODIM, NUSERS);
    agg_h_k<<<(NUSERS+15)/16,256,0,stream>>>(Hmsg_i, NREL*ODIM, Hroot_u, ODIM,
        adj, off_u, b2_iu, user2, NUSERS);
  } else {
    // fallback M-scheme
    ushortT* Mbuf = (ushortT*)big;
    long long c2 = (long long)(avail / ((size_t)6*HID*2));
    int CH = (int)(c2 > NUSERS ? NUSERS : c2); CH &= ~127; if(CH < 128) CH = 128;
    for(int lo=0; lo<NITEMS; lo+=CH){
      int cn = imin(CH, NITEMS-lo);
      agg_m_k<HID><<<(cn+3)/4,256,0,stream>>>(h1u, h1i, adj, off_i, Mbuf, lo, cn);
      gemm2v_k<64,64,false,false><<<dim3(1,(cn+63)/64),256,0,stream>>>(
          Mbuf, 6*HID, Mbuf, 6*HID, 6*HID, BT2ui, 6*HID, b2_ui, item2 + (size_t)lo*ODIM, ODIM, cn);
    }
    for(int lo=0; lo<NUSERS; lo+=CH){
      int cn = imin(CH, NUSERS-lo);
      agg_m_k<HID><<<(cn+3)/4,256,0,stream>>>(h1i, h1u, adj, off_u, Mbuf, lo, cn);
      gemm2v_k<64,64,false,false><<<dim3(1,(cn+63)/64),256,0,stream>>>(
          Mbuf, 6*HID, Mbuf, 6*HID, 6*HID, BT2iu, 6*HID, b2_iu, user2 + (size_t)lo*ODIM, ODIM, cn);
    }
  }
}